// Round 3
// baseline (708.948 us; speedup 1.0000x reference)
//
#include <hip/hip_runtime.h>
#include <cstdint>
#include <cstddef>

#define T_TOTAL   131072
#define NWORDS    32768
#define WDIM      1024
#define CDIM      256
#define HID       512
#define NEMB      40
#define KDIM      1024
#define NDIM      1024

#define BM 128
#define BN 128
#define BK 32
#define NK (KDIM / BK)
#define EPS 132   // epilogue LDS row stride (floats): 528B -> bank-even

typedef __attribute__((ext_vector_type(8))) short bf16x8;
typedef __attribute__((ext_vector_type(4))) float f32x4;
typedef __attribute__((ext_vector_type(4))) unsigned short u16x4;

__device__ __forceinline__ unsigned short f2bf(float x) {
  union { float f; unsigned int u; } v; v.f = x;
  unsigned int r = v.u + 0x7fffu + ((v.u >> 16) & 1u);   // RNE
  return (unsigned short)(r >> 16);
}
__device__ __forceinline__ float bf2f(unsigned short b) {
  union { float f; unsigned int u; } v; v.u = ((unsigned int)b) << 16;
  return v.f;
}

__device__ __forceinline__ void gld16(const void* src, void* lds) {
  __builtin_amdgcn_global_load_lds(
      (const __attribute__((address_space(1))) unsigned int*)src,
      (__attribute__((address_space(3))) unsigned int*)lds, 16, 0, 0);
}

__device__ __forceinline__ void nt_store_f2(float* p, float a, float b) {
  union { float f[2]; unsigned long long u; } v;
  v.f[0] = a; v.f[1] = b;
  __builtin_nontemporal_store(v.u, (unsigned long long*)p);
}

// ---------------- index build ----------------
__global__ __launch_bounds__(256) void k_zero(int* __restrict__ p, int n) {
  int i = blockIdx.x * 256 + threadIdx.x;
  if (i < n) p[i] = 0;
}

__global__ __launch_bounds__(256) void k_hist(const int* __restrict__ wid,
                                              int* __restrict__ cnt) {
  int i = blockIdx.x * 256 + threadIdx.x;
  atomicAdd(&cnt[wid[i]], 1);
}

__global__ __launch_bounds__(1024) void k_scan(const int* __restrict__ cnt,
                                               int* __restrict__ offs,
                                               int* __restrict__ cur) {
  __shared__ int ps[1024];
  int tid = threadIdx.x;
  int base = tid * 32;
  int s = 0;
  for (int i = 0; i < 32; ++i) s += cnt[base + i];
  ps[tid] = s;
  __syncthreads();
  for (int d = 1; d < 1024; d <<= 1) {
    int add = (tid >= d) ? ps[tid - d] : 0;
    __syncthreads();
    ps[tid] += add;
    __syncthreads();
  }
  int run = (tid > 0) ? ps[tid - 1] : 0;
  for (int i = 0; i < 32; ++i) {
    int v = cnt[base + i];
    offs[base + i] = run;
    cur[base + i] = run;
    run += v;
  }
  if (tid == 1023) offs[NWORDS] = run;
}

__global__ __launch_bounds__(256) void k_scatter(const int* __restrict__ wid,
                                                 int* __restrict__ cur,
                                                 int* __restrict__ perm) {
  int i = blockIdx.x * 256 + threadIdx.x;
  int w = wid[i];
  int p = atomicAdd(&cur[w], 1);
  perm[p] = i;  // order within a word is nondeterministic; output values are not
}

// ---------------- LSTM h table: 40 x 512 ----------------
__global__ __launch_bounds__(256) void k_prep_h(const float* __restrict__ E,
                                                const float* __restrict__ W_ih,
                                                const float* __restrict__ b_ih,
                                                const float* __restrict__ b_hh,
                                                float* __restrict__ h) {
  int e = blockIdx.x;
  int tid = threadIdx.x;
  __shared__ float x[CDIM];
  x[tid] = E[e * CDIM + tid];
  __syncthreads();
  const float4* xv = (const float4*)x;
#pragma unroll
  for (int rep = 0; rep < 2; ++rep) {
    int j = rep * 256 + tid;                       // j in [0,512)
    float si = b_ih[j] + b_hh[j];
    float sg = b_ih[1024 + j] + b_hh[1024 + j];
    float so = b_ih[1536 + j] + b_hh[1536 + j];
    const float4* wi = (const float4*)&W_ih[(size_t)j * CDIM];
    const float4* wg = (const float4*)&W_ih[(size_t)(1024 + j) * CDIM];
    const float4* wo = (const float4*)&W_ih[(size_t)(1536 + j) * CDIM];
    for (int k = 0; k < CDIM / 4; ++k) {
      float4 d = xv[k];
      float4 a = wi[k]; si += a.x*d.x + a.y*d.y + a.z*d.z + a.w*d.w;
      float4 b = wg[k]; sg += b.x*d.x + b.y*d.y + b.z*d.z + b.w*d.w;
      float4 c = wo[k]; so += c.x*d.x + c.y*d.y + c.z*d.z + c.w*d.w;
    }
    float iv = 1.f / (1.f + expf(-si));
    float cv = iv * tanhf(sg);
    float ov = 1.f / (1.f + expf(-so));
    h[e * HID + j] = ov * tanhf(cv);
  }
}

// ---------------- Hc table: 40 x 1024 = W_lin[:,1024:] @ h + b_lin ----------------
__global__ __launch_bounds__(256) void k_prep_hc2(const float* __restrict__ h,
                                                  const float* __restrict__ W_lin,
                                                  const float* __restrict__ b_lin,
                                                  float* __restrict__ Hc) {
  int e = blockIdx.x >> 2;
  int chunk = blockIdx.x & 3;
  int tid = threadIdx.x;
  __shared__ float hs[HID];
  hs[tid] = h[e * HID + tid];
  hs[256 + tid] = h[e * HID + 256 + tid];
  __syncthreads();
  int n = chunk * 256 + tid;
  float s = b_lin[n];
  const float4* wl = (const float4*)&W_lin[(size_t)n * 1536 + 1024];
  const float4* hv = (const float4*)hs;
  for (int k = 0; k < HID / 4; ++k) {
    float4 a = wl[k], b = hv[k];
    s += a.x*b.x + a.y*b.y + a.z*b.z + a.w*b.w;
  }
  Hc[e * NDIM + n] = s;
}

// ---------------- fp32 -> (hi,lo) bf16 split, cols [0,1024) of a row-major mat ----------------
__global__ __launch_bounds__(256) void k_conv(const float* __restrict__ src, long ld,
                                              unsigned short* __restrict__ hi,
                                              unsigned short* __restrict__ lo) {
  long idx = ((long)blockIdx.x * 256 + threadIdx.x) * 4;
  long r = idx >> 10;
  int c = (int)(idx & 1023);
  const float4 v = *(const float4*)&src[r * ld + c];
  unsigned short h0 = f2bf(v.x), h1 = f2bf(v.y), h2 = f2bf(v.z), h3 = f2bf(v.w);
  u16x4 H = {h0, h1, h2, h3};
  u16x4 L = {f2bf(v.x - bf2f(h0)), f2bf(v.y - bf2f(h1)),
             f2bf(v.z - bf2f(h2)), f2bf(v.w - bf2f(h3))};
  *(u16x4*)&hi[idx] = H;
  *(u16x4*)&lo[idx] = L;
}

// ---------------- main GEMM (dedup'd words) + coalesced scatter epilogue ----------------
// P[m][n] = sum_k we[m][k] * W_lin[n][k]  via split-bf16 3-MFMA emulation.
// PRECONV path: double-buffered LDS (2 x 32KB), prefetch next K-tile before compute,
// XOR slot-swizzle (slot' = slot ^ ((row>>1)&3)) applied on the GLOBAL source (LDS
// dest stays linear, required by global_load_lds) and on the fragment reads.
template <bool PRECONV>
__global__ __launch_bounds__(256) void k_gemm_scatter(
    const float* __restrict__ Af,
    const unsigned short* __restrict__ Ah, const unsigned short* __restrict__ Al,
    const unsigned short* __restrict__ Bh, const unsigned short* __restrict__ Bl,
    const float* __restrict__ Hc, const int* __restrict__ offs,
    const int* __restrict__ perm, const int* __restrict__ cid,
    float* __restrict__ out) {
  // buf0 = smem[0,32K): [A-hi 8K][A-lo 8K][B-hi 8K][B-lo 8K]; buf1 = smem[32K,64K)
  // Epilogue overlays smem[0, 64*EPS*4).
  __shared__ __align__(16) char smem[65536];

  int nwg = gridDim.x;
  int bid = blockIdx.x;
  int cpx = nwg >> 3;                       // XCD-contiguous swizzle (nwg % 8 == 0)
  int swz = (bid & 7) * cpx + (bid >> 3);
  int bn = swz & 7;                         // NDIM/BN == 8
  int bm = swz >> 3;

  int tid = threadIdx.x;
  int lane = tid & 63;
  int w = tid >> 6;
  int wm = w >> 1, wn = w & 1;
  int fr = lane & 15, fq = lane >> 4;

  size_t arow0 = (size_t)bm * BM;
  size_t brow0 = (size_t)bn * BN;

  f32x4 acc[4][4];
#pragma unroll
  for (int i = 0; i < 4; ++i)
#pragma unroll
    for (int j = 0; j < 4; ++j) acc[i][j] = (f32x4)0.0f;

  if (PRECONV) {
    // ---- loop-invariant staging descriptors (2 x 16B per thread per tile)
    size_t aSrc[2], bSrc[2];
    int ldsOff[2];
#pragma unroll
    for (int is = 0; is < 2; ++is) {
      int off = is * 4096 + tid * 16;
      int r = off >> 6;                     // row 0..127
      int sp = (off >> 4) & 3;              // physical 16B slot in row
      int colE = ((sp ^ ((r >> 1) & 3)) << 3);  // swizzled source col (bf16 elems)
      aSrc[is] = (arow0 + r) * KDIM + colE;
      bSrc[is] = (brow0 + r) * KDIM + colE;
      ldsOff[is] = is * 4096 + w * 1024;    // wave-uniform LDS base
    }
    // ---- loop-invariant fragment read offsets (swizzled)
    int aOff[4], bOff[4];
#pragma unroll
    for (int mi = 0; mi < 4; ++mi) {
      int row = wm * 64 + mi * 16 + fr;
      aOff[mi] = row * 64 + ((fq ^ ((row >> 1) & 3)) << 4);
    }
#pragma unroll
    for (int ni = 0; ni < 4; ++ni) {
      int row = wn * 64 + ni * 16 + fr;
      bOff[ni] = row * 64 + ((fq ^ ((row >> 1) & 3)) << 4);
    }

    auto STAGE = [&](int buf, int k0) {
      char* b = smem + buf * 32768;
#pragma unroll
      for (int is = 0; is < 2; ++is) {
        gld16(Ah + aSrc[is] + k0, b + ldsOff[is]);
        gld16(Al + aSrc[is] + k0, b + 8192 + ldsOff[is]);
        gld16(Bh + bSrc[is] + k0, b + 16384 + ldsOff[is]);
        gld16(Bl + bSrc[is] + k0, b + 24576 + ldsOff[is]);
      }
    };

    STAGE(0, 0);
    __syncthreads();
    for (int t = 0; t < NK; ++t) {
      char* bufc = smem + (t & 1) * 32768;
      if (t + 1 < NK) STAGE((t + 1) & 1, (t + 1) * BK);

      bf16x8 fah[4], fal[4], fbh[4], fbl[4];
#pragma unroll
      for (int ni = 0; ni < 4; ++ni) {
        fbh[ni] = *(const bf16x8*)(bufc + 16384 + bOff[ni]);
        fbl[ni] = *(const bf16x8*)(bufc + 24576 + bOff[ni]);
      }
#pragma unroll
      for (int mi = 0; mi < 4; ++mi) {
        fah[mi] = *(const bf16x8*)(bufc + aOff[mi]);
        fal[mi] = *(const bf16x8*)(bufc + 8192 + aOff[mi]);
      }
#pragma unroll
      for (int mi = 0; mi < 4; ++mi)
#pragma unroll
        for (int ni = 0; ni < 4; ++ni) {
          acc[mi][ni] = __builtin_amdgcn_mfma_f32_16x16x32_bf16(fah[mi], fbh[ni], acc[mi][ni], 0, 0, 0);
          acc[mi][ni] = __builtin_amdgcn_mfma_f32_16x16x32_bf16(fah[mi], fbl[ni], acc[mi][ni], 0, 0, 0);
          acc[mi][ni] = __builtin_amdgcn_mfma_f32_16x16x32_bf16(fal[mi], fbh[ni], acc[mi][ni], 0, 0, 0);
        }
      __syncthreads();
    }
  } else {
    // Fallback: single-buffer, split A from fp32 in-kernel (legacy structure)
    char* sA  = smem;
    char* sBh = smem + 16384;
    char* sBl = smem + 24576;
    int kb = fq * 8;
    for (int k0 = 0; k0 < KDIM; k0 += BK) {
#pragma unroll
      for (int is = 0; is < 2; ++is) {
        int off = is * 4096 + tid * 16;
        int r = off >> 6;
        int col = (off & 63) >> 1;
        int ldsoff = is * 4096 + w * 1024;
        gld16(Bh + (brow0 + r) * KDIM + k0 + col, sBh + ldsoff);
        gld16(Bl + (brow0 + r) * KDIM + k0 + col, sBl + ldsoff);
      }
#pragma unroll
      for (int is = 0; is < 4; ++is) {
        int off = is * 4096 + tid * 16;
        int r = off >> 7;
        int sl = (off >> 4) & 7;
        int col = ((sl ^ (r & 7)) << 2);    // floats
        int ldsoff = is * 4096 + w * 1024;
        gld16(Af + (arow0 + r) * KDIM + k0 + col, sA + ldsoff);
      }
      __syncthreads();

      bf16x8 fah[4], fal[4], fbh[4], fbl[4];
#pragma unroll
      for (int ni = 0; ni < 4; ++ni) {
        int row = wn * 64 + ni * 16 + fr;
        fbh[ni] = *(const bf16x8*)(sBh + row * 64 + (kb << 1));
        fbl[ni] = *(const bf16x8*)(sBl + row * 64 + (kb << 1));
      }
#pragma unroll
      for (int mi = 0; mi < 4; ++mi) {
        int row = wm * 64 + mi * 16 + fr;
        int s1 = (kb >> 2) ^ (row & 7);
        int s2 = ((kb >> 2) + 1) ^ (row & 7);
        float4 v1 = *(const float4*)(sA + row * 128 + s1 * 16);
        float4 v2 = *(const float4*)(sA + row * 128 + s2 * 16);
        float f[8] = {v1.x, v1.y, v1.z, v1.w, v2.x, v2.y, v2.z, v2.w};
        union { bf16x8 v; unsigned short u[8]; } H, L;
#pragma unroll
        for (int q = 0; q < 8; ++q) {
          unsigned short hq = f2bf(f[q]);
          H.u[q] = hq;
          L.u[q] = f2bf(f[q] - bf2f(hq));
        }
        fah[mi] = H.v;
        fal[mi] = L.v;
      }
#pragma unroll
      for (int mi = 0; mi < 4; ++mi)
#pragma unroll
        for (int ni = 0; ni < 4; ++ni) {
          acc[mi][ni] = __builtin_amdgcn_mfma_f32_16x16x32_bf16(fah[mi], fbh[ni], acc[mi][ni], 0, 0, 0);
          acc[mi][ni] = __builtin_amdgcn_mfma_f32_16x16x32_bf16(fah[mi], fbl[ni], acc[mi][ni], 0, 0, 0);
          acc[mi][ni] = __builtin_amdgcn_mfma_f32_16x16x32_bf16(fal[mi], fbh[ni], acc[mi][ni], 0, 0, 0);
        }
      __syncthreads();
    }
  }

  // ---- epilogue: stage P into LDS (two 64-row halves), coalesced scatter
  // C/D frag layout: row = wm*64 + mi*16 + fq*4 + j, col = wn*64 + ni*16 + fr
  float* ep = (float*)smem;
#pragma unroll
  for (int half = 0; half < 2; ++half) {
    if (wm == half) {
#pragma unroll
      for (int mi = 0; mi < 4; ++mi)
#pragma unroll
        for (int ni = 0; ni < 4; ++ni)
#pragma unroll
          for (int j = 0; j < 4; ++j) {
            int r = mi * 16 + fq * 4 + j;
            int c = wn * 64 + ni * 16 + fr;
            ep[r * EPS + c] = acc[mi][ni][j];
          }
    }
    __syncthreads();
    // rows [half*64, half*64+64): wave w handles rows w, w+4, ...
    for (int m = w; m < 64; m += 4) {
      int gm = (int)arow0 + half * 64 + m;
      int beg = offs[gm];
      int end = offs[gm + 1];
      if (beg == end) continue;
      float2 pv = *(const float2*)&ep[m * EPS + lane * 2];
      for (int p = beg; p < end; ++p) {
        int t = perm[p];
        int c = cid[t];
        float2 hv = *(const float2*)&Hc[(size_t)c * NDIM + brow0 + lane * 2];
        nt_store_f2(&out[(size_t)t * NDIM + brow0 + lane * 2],
                    fmaxf(pv.x + hv.x, 0.f), fmaxf(pv.y + hv.y, 0.f));
      }
    }
    __syncthreads();
  }
}

extern "C" void kernel_launch(void* const* d_in, const int* in_sizes, int n_in,
                              void* d_out, int out_size, void* d_ws, size_t ws_size,
                              hipStream_t stream) {
  (void)in_sizes; (void)n_in; (void)out_size;
  const float* word_emb = (const float*)d_in[0];
  const int*   char_ids = (const int*)d_in[1];
  const int*   word_ids = (const int*)d_in[2];
  const float* E        = (const float*)d_in[3];
  const float* W_ih     = (const float*)d_in[4];
  const float* b_ih     = (const float*)d_in[5];
  const float* b_hh     = (const float*)d_in[6];
  const float* W_lin    = (const float*)d_in[7];
  const float* b_lin    = (const float*)d_in[8];
  float* out = (float*)d_out;
  char* ws = (char*)d_ws;

  size_t o = 0;
  auto alloc = [&](size_t b) { size_t r = o; o = (o + b + 255) & ~(size_t)255; return r; };
  size_t oHc   = alloc((size_t)NEMB * NDIM * 4);
  size_t oH    = alloc((size_t)NEMB * HID * 4);
  size_t oBh   = alloc((size_t)NDIM * KDIM * 2);
  size_t oBl   = alloc((size_t)NDIM * KDIM * 2);
  size_t oCnt  = alloc((size_t)NWORDS * 4);
  size_t oOffs = alloc((size_t)(NWORDS + 1) * 4);
  size_t oCur  = alloc((size_t)NWORDS * 4);
  size_t oPerm = alloc((size_t)T_TOTAL * 4);
  size_t oAh   = alloc((size_t)NWORDS * KDIM * 2);
  size_t oAl   = alloc((size_t)NWORDS * KDIM * 2);
  size_t needA = o;

  float* Hc          = (float*)(ws + oHc);
  float* hbuf        = (float*)(ws + oH);
  unsigned short* Bh = (unsigned short*)(ws + oBh);
  unsigned short* Bl = (unsigned short*)(ws + oBl);
  int* cnt   = (int*)(ws + oCnt);
  int* offsp = (int*)(ws + oOffs);
  int* cur   = (int*)(ws + oCur);
  int* perm  = (int*)(ws + oPerm);
  unsigned short* Ah = (unsigned short*)(ws + oAh);
  unsigned short* Al = (unsigned short*)(ws + oAl);

  bool preconv = (ws_size >= needA);

  // inverted index word -> char positions
  k_zero<<<(NWORDS + 255) / 256, 256, 0, stream>>>(cnt, NWORDS);
  k_hist<<<T_TOTAL / 256, 256, 0, stream>>>(word_ids, cnt);
  k_scan<<<1, 1024, 0, stream>>>(cnt, offsp, cur);
  k_scatter<<<T_TOTAL / 256, 256, 0, stream>>>(word_ids, cur, perm);

  // LSTM-branch table + W1 split
  k_prep_h<<<NEMB, 256, 0, stream>>>(E, W_ih, b_ih, b_hh, hbuf);
  k_prep_hc2<<<NEMB * 4, 256, 0, stream>>>(hbuf, W_lin, b_lin, Hc);
  k_conv<<<(NDIM * KDIM / 4) / 256, 256, 0, stream>>>(W_lin, 1536L, Bh, Bl);

  int grid = (NWORDS / BM) * (NDIM / BN);  // 2048
  if (preconv) {
    k_conv<<<((size_t)NWORDS * KDIM / 4) / 256, 256, 0, stream>>>(word_emb, 1024L, Ah, Al);
    k_gemm_scatter<true><<<grid, 256, 0, stream>>>(
        word_emb, Ah, Al, Bh, Bl, Hc, offsp, perm, char_ids, out);
  } else {
    k_gemm_scatter<false><<<grid, 256, 0, stream>>>(
        word_emb, Ah, Al, Bh, Bl, Hc, offsp, perm, char_ids, out);
  }
}

// Round 4
// 566.362 us; speedup vs baseline: 1.2518x; 1.2518x over previous
//
#include <hip/hip_runtime.h>
#include <cstdint>
#include <cstddef>

#define T_TOTAL   131072
#define NWORDS    32768
#define WDIM      1024
#define CDIM      256
#define HID       512
#define NEMB      40
#define KDIM      1024
#define NDIM      1024

#define BM 128
#define BN 128
#define BK 32
#define NK (KDIM / BK)
#define EPS 132   // epilogue LDS row stride (floats): 528B -> bank-even

typedef __attribute__((ext_vector_type(8))) short bf16x8;
typedef __attribute__((ext_vector_type(4))) float f32x4;
typedef __attribute__((ext_vector_type(4))) unsigned short u16x4;

__device__ __forceinline__ unsigned short f2bf(float x) {
  union { float f; unsigned int u; } v; v.f = x;
  unsigned int r = v.u + 0x7fffu + ((v.u >> 16) & 1u);   // RNE
  return (unsigned short)(r >> 16);
}
__device__ __forceinline__ float bf2f(unsigned short b) {
  union { float f; unsigned int u; } v; v.u = ((unsigned int)b) << 16;
  return v.f;
}

__device__ __forceinline__ void gld16(const void* src, void* lds) {
  __builtin_amdgcn_global_load_lds(
      (const __attribute__((address_space(1))) unsigned int*)src,
      (__attribute__((address_space(3))) unsigned int*)lds, 16, 0, 0);
}

__device__ __forceinline__ void nt_store_f2(float* p, float a, float b) {
  union { float f[2]; unsigned long long u; } v;
  v.f[0] = a; v.f[1] = b;
  __builtin_nontemporal_store(v.u, (unsigned long long*)p);
}

// ---------------- index build ----------------
__global__ __launch_bounds__(256) void k_zero(int* __restrict__ p, int n) {
  int i = blockIdx.x * 256 + threadIdx.x;
  if (i < n) p[i] = 0;
}

__global__ __launch_bounds__(256) void k_hist(const int* __restrict__ wid,
                                              int* __restrict__ cnt) {
  int i = blockIdx.x * 256 + threadIdx.x;
  atomicAdd(&cnt[wid[i]], 1);
}

__global__ __launch_bounds__(1024) void k_scan(const int* __restrict__ cnt,
                                               int* __restrict__ offs,
                                               int* __restrict__ cur) {
  __shared__ int ps[1024];
  int tid = threadIdx.x;
  int base = tid * 32;
  int s = 0;
  for (int i = 0; i < 32; ++i) s += cnt[base + i];
  ps[tid] = s;
  __syncthreads();
  for (int d = 1; d < 1024; d <<= 1) {
    int add = (tid >= d) ? ps[tid - d] : 0;
    __syncthreads();
    ps[tid] += add;
    __syncthreads();
  }
  int run = (tid > 0) ? ps[tid - 1] : 0;
  for (int i = 0; i < 32; ++i) {
    int v = cnt[base + i];
    offs[base + i] = run;
    cur[base + i] = run;
    run += v;
  }
  if (tid == 1023) offs[NWORDS] = run;
}

__global__ __launch_bounds__(256) void k_scatter(const int* __restrict__ wid,
                                                 int* __restrict__ cur,
                                                 int* __restrict__ perm) {
  int i = blockIdx.x * 256 + threadIdx.x;
  int w = wid[i];
  int p = atomicAdd(&cur[w], 1);
  perm[p] = i;  // order within a word is nondeterministic; output values are not
}

// ---------------- LSTM h table: 40 x 512 ----------------
__global__ __launch_bounds__(256) void k_prep_h(const float* __restrict__ E,
                                                const float* __restrict__ W_ih,
                                                const float* __restrict__ b_ih,
                                                const float* __restrict__ b_hh,
                                                float* __restrict__ h) {
  int e = blockIdx.x;
  int tid = threadIdx.x;
  __shared__ float x[CDIM];
  x[tid] = E[e * CDIM + tid];
  __syncthreads();
  const float4* xv = (const float4*)x;
#pragma unroll
  for (int rep = 0; rep < 2; ++rep) {
    int j = rep * 256 + tid;                       // j in [0,512)
    float si = b_ih[j] + b_hh[j];
    float sg = b_ih[1024 + j] + b_hh[1024 + j];
    float so = b_ih[1536 + j] + b_hh[1536 + j];
    const float4* wi = (const float4*)&W_ih[(size_t)j * CDIM];
    const float4* wg = (const float4*)&W_ih[(size_t)(1024 + j) * CDIM];
    const float4* wo = (const float4*)&W_ih[(size_t)(1536 + j) * CDIM];
    for (int k = 0; k < CDIM / 4; ++k) {
      float4 d = xv[k];
      float4 a = wi[k]; si += a.x*d.x + a.y*d.y + a.z*d.z + a.w*d.w;
      float4 b = wg[k]; sg += b.x*d.x + b.y*d.y + b.z*d.z + b.w*d.w;
      float4 c = wo[k]; so += c.x*d.x + c.y*d.y + c.z*d.z + c.w*d.w;
    }
    float iv = 1.f / (1.f + expf(-si));
    float cv = iv * tanhf(sg);
    float ov = 1.f / (1.f + expf(-so));
    h[e * HID + j] = ov * tanhf(cv);
  }
}

// ---------------- Hc table: 40 x 1024 = W_lin[:,1024:] @ h + b_lin ----------------
__global__ __launch_bounds__(256) void k_prep_hc2(const float* __restrict__ h,
                                                  const float* __restrict__ W_lin,
                                                  const float* __restrict__ b_lin,
                                                  float* __restrict__ Hc) {
  int e = blockIdx.x >> 2;
  int chunk = blockIdx.x & 3;
  int tid = threadIdx.x;
  __shared__ float hs[HID];
  hs[tid] = h[e * HID + tid];
  hs[256 + tid] = h[e * HID + 256 + tid];
  __syncthreads();
  int n = chunk * 256 + tid;
  float s = b_lin[n];
  const float4* wl = (const float4*)&W_lin[(size_t)n * 1536 + 1024];
  const float4* hv = (const float4*)hs;
  for (int k = 0; k < HID / 4; ++k) {
    float4 a = wl[k], b = hv[k];
    s += a.x*b.x + a.y*b.y + a.z*b.z + a.w*b.w;
  }
  Hc[e * NDIM + n] = s;
}

// ---------------- fp32 -> (hi,lo) bf16 split, cols [0,1024) of a row-major mat ----------------
__global__ __launch_bounds__(256) void k_conv(const float* __restrict__ src, long ld,
                                              unsigned short* __restrict__ hi,
                                              unsigned short* __restrict__ lo) {
  long idx = ((long)blockIdx.x * 256 + threadIdx.x) * 4;
  long r = idx >> 10;
  int c = (int)(idx & 1023);
  const float4 v = *(const float4*)&src[r * ld + c];
  unsigned short h0 = f2bf(v.x), h1 = f2bf(v.y), h2 = f2bf(v.z), h3 = f2bf(v.w);
  u16x4 H = {h0, h1, h2, h3};
  u16x4 L = {f2bf(v.x - bf2f(h0)), f2bf(v.y - bf2f(h1)),
             f2bf(v.z - bf2f(h2)), f2bf(v.w - bf2f(h3))};
  *(u16x4*)&hi[idx] = H;
  *(u16x4*)&lo[idx] = L;
}

// ---------------- main GEMM (dedup'd words) + coalesced scatter epilogue ----------------
// P[m][n] = sum_k we[m][k] * W_lin[n][k]  via split-bf16 3-MFMA emulation.
// 512 threads / 8 waves (2M x 4N, wave tile 64x32), 2 x 32KB LDS double-buffer,
// counted-vmcnt pipeline (no vmcnt(0) drain in main loop), raw s_barrier.
// XOR slot-swizzle (slot' = slot ^ ((row>>1)&3)) on the GLOBAL source (LDS dest
// linear, required by global_load_lds) and on the fragment reads -> 0 conflicts.
template <bool PRECONV>
__global__ __launch_bounds__(512, 4) void k_gemm_scatter(
    const float* __restrict__ Af,
    const unsigned short* __restrict__ Ah, const unsigned short* __restrict__ Al,
    const unsigned short* __restrict__ Bh, const unsigned short* __restrict__ Bl,
    const float* __restrict__ Hc, const int* __restrict__ offs,
    const int* __restrict__ perm, const int* __restrict__ cid,
    float* __restrict__ out) {
  // buf = smem + b*32768: [A-hi 8K][A-lo 8K][B-hi 8K][B-lo 8K]
  // Epilogue overlays smem[0, 64*EPS*4).
  __shared__ __align__(16) char smem[65536];

  int nwg = gridDim.x;
  int bid = blockIdx.x;
  int cpx = nwg >> 3;                       // XCD-contiguous swizzle (nwg % 8 == 0)
  int swz = (bid & 7) * cpx + (bid >> 3);
  int bn = swz & 7;                         // NDIM/BN == 8
  int bm = swz >> 3;

  int tid = threadIdx.x;
  int lane = tid & 63;
  int w = tid >> 6;                         // 0..7
  int wm = w >> 2, wn = w & 3;              // 2 x 4 wave grid; wave tile 64x32
  int fr = lane & 15, fq = lane >> 4;

  size_t arow0 = (size_t)bm * BM;
  size_t brow0 = (size_t)bn * BN;

  f32x4 acc[4][2];
#pragma unroll
  for (int i = 0; i < 4; ++i)
#pragma unroll
    for (int j = 0; j < 2; ++j) acc[i][j] = (f32x4)0.0f;

  if (PRECONV) {
    // ---- loop-invariant staging descriptors (1 x 16B per thread per sub-array)
    int off = tid * 16;                     // 0..8191
    int r = off >> 6;                       // row 0..127
    int sp = (off >> 4) & 3;                // physical 16B slot in 64B row
    int colE = ((sp ^ ((r >> 1) & 3)) << 3);  // swizzled source col (bf16 elems)
    size_t aSrc = (arow0 + r) * KDIM + colE;
    size_t bSrc = (brow0 + r) * KDIM + colE;
    int ldsOff = w * 1024;                  // wave-uniform LDS base (+ lane*16 implicit)

    // ---- loop-invariant fragment read offsets (swizzled)
    int aOff[4], bOff[2];
#pragma unroll
    for (int mi = 0; mi < 4; ++mi) {
      int row = wm * 64 + mi * 16 + fr;
      aOff[mi] = row * 64 + ((fq ^ ((row >> 1) & 3)) << 4);
    }
#pragma unroll
    for (int ni = 0; ni < 2; ++ni) {
      int row = wn * 32 + ni * 16 + fr;
      bOff[ni] = row * 64 + ((fq ^ ((row >> 1) & 3)) << 4);
    }

    auto STAGE = [&](int buf, int k0) {
      char* b = smem + buf * 32768;
      gld16(Ah + aSrc + k0, b + ldsOff);
      gld16(Al + aSrc + k0, b + 8192 + ldsOff);
      gld16(Bh + bSrc + k0, b + 16384 + ldsOff);
      gld16(Bl + bSrc + k0, b + 24576 + ldsOff);
    };

    STAGE(0, 0);                            // 4 loads in flight
    for (int t = 0; t < NK; ++t) {
      char* bufc = smem + (t & 1) * 32768;
      if (t + 1 < NK) {
        STAGE((t + 1) & 1, (t + 1) * BK);   // +4 -> 8 in flight
        asm volatile("s_waitcnt vmcnt(4)" ::: "memory");  // tile t landed, t+1 flying
      } else {
        asm volatile("s_waitcnt vmcnt(0)" ::: "memory");
      }
      __builtin_amdgcn_s_barrier();
      __builtin_amdgcn_sched_barrier(0);

      bf16x8 fah[4], fal[4], fbh[2], fbl[2];
#pragma unroll
      for (int ni = 0; ni < 2; ++ni) {
        fbh[ni] = *(const bf16x8*)(bufc + 16384 + bOff[ni]);
        fbl[ni] = *(const bf16x8*)(bufc + 24576 + bOff[ni]);
      }
#pragma unroll
      for (int mi = 0; mi < 4; ++mi) {
        fah[mi] = *(const bf16x8*)(bufc + aOff[mi]);
        fal[mi] = *(const bf16x8*)(bufc + 8192 + aOff[mi]);
      }
#pragma unroll
      for (int mi = 0; mi < 4; ++mi)
#pragma unroll
        for (int ni = 0; ni < 2; ++ni) {
          acc[mi][ni] = __builtin_amdgcn_mfma_f32_16x16x32_bf16(fah[mi], fbh[ni], acc[mi][ni], 0, 0, 0);
          acc[mi][ni] = __builtin_amdgcn_mfma_f32_16x16x32_bf16(fah[mi], fbl[ni], acc[mi][ni], 0, 0, 0);
          acc[mi][ni] = __builtin_amdgcn_mfma_f32_16x16x32_bf16(fal[mi], fbh[ni], acc[mi][ni], 0, 0, 0);
        }
      __builtin_amdgcn_sched_barrier(0);    // keep ds_reads above this barrier
      __builtin_amdgcn_s_barrier();         // protect buf t from tile t+2 staging
    }
  } else {
    // Fallback: single-buffer, split A from fp32 in-kernel (compat path)
    char* sA  = smem;                       // fp32 128x32, 8-slot swizzled rows
    char* sBh = smem + 16384;
    char* sBl = smem + 24576;
    int kb = fq * 8;
    for (int k0 = 0; k0 < KDIM; k0 += BK) {
      {
        int off = tid * 16;
        int r = off >> 6;
        int col = (off & 63) >> 1;
        int ldsoff = w * 1024;
        gld16(Bh + (brow0 + r) * KDIM + k0 + col, sBh + ldsoff);
        gld16(Bl + (brow0 + r) * KDIM + k0 + col, sBl + ldsoff);
      }
#pragma unroll
      for (int is = 0; is < 2; ++is) {
        int off = is * 8192 + tid * 16;
        int r = off >> 7;
        int sl = (off >> 4) & 7;
        int col = ((sl ^ (r & 7)) << 2);    // floats
        int ldsoff = is * 8192 + w * 1024;
        gld16(Af + (arow0 + r) * KDIM + k0 + col, sA + ldsoff);
      }
      __syncthreads();

      bf16x8 fah[4], fal[4], fbh[2], fbl[2];
#pragma unroll
      for (int ni = 0; ni < 2; ++ni) {
        int row = wn * 32 + ni * 16 + fr;
        fbh[ni] = *(const bf16x8*)(sBh + row * 64 + (kb << 1));
        fbl[ni] = *(const bf16x8*)(sBl + row * 64 + (kb << 1));
      }
#pragma unroll
      for (int mi = 0; mi < 4; ++mi) {
        int row = wm * 64 + mi * 16 + fr;
        int s1 = (kb >> 2) ^ (row & 7);
        int s2 = ((kb >> 2) + 1) ^ (row & 7);
        float4 v1 = *(const float4*)(sA + row * 128 + s1 * 16);
        float4 v2 = *(const float4*)(sA + row * 128 + s2 * 16);
        float f[8] = {v1.x, v1.y, v1.z, v1.w, v2.x, v2.y, v2.z, v2.w};
        union { bf16x8 v; unsigned short u[8]; } H, L;
#pragma unroll
        for (int q = 0; q < 8; ++q) {
          unsigned short hq = f2bf(f[q]);
          H.u[q] = hq;
          L.u[q] = f2bf(f[q] - bf2f(hq));
        }
        fah[mi] = H.v;
        fal[mi] = L.v;
      }
#pragma unroll
      for (int mi = 0; mi < 4; ++mi)
#pragma unroll
        for (int ni = 0; ni < 2; ++ni) {
          acc[mi][ni] = __builtin_amdgcn_mfma_f32_16x16x32_bf16(fah[mi], fbh[ni], acc[mi][ni], 0, 0, 0);
          acc[mi][ni] = __builtin_amdgcn_mfma_f32_16x16x32_bf16(fah[mi], fbl[ni], acc[mi][ni], 0, 0, 0);
          acc[mi][ni] = __builtin_amdgcn_mfma_f32_16x16x32_bf16(fal[mi], fbh[ni], acc[mi][ni], 0, 0, 0);
        }
      __syncthreads();
    }
  }

  // ---- epilogue: stage P into LDS (two 64-row halves), coalesced scatter
  // C/D frag layout: row = wm*64 + mi*16 + fq*4 + j, col = wn*32 + ni*16 + fr
  float* ep = (float*)smem;
  __syncthreads();   // full drain before overlaying staging buffers
#pragma unroll
  for (int half = 0; half < 2; ++half) {
    if (wm == half) {
#pragma unroll
      for (int mi = 0; mi < 4; ++mi)
#pragma unroll
        for (int ni = 0; ni < 2; ++ni)
#pragma unroll
          for (int j = 0; j < 4; ++j) {
            int r = mi * 16 + fq * 4 + j;
            int c = wn * 32 + ni * 16 + fr;
            ep[r * EPS + c] = acc[mi][ni][j];
          }
    }
    __syncthreads();
    // rows [half*64, half*64+64): wave w handles rows w, w+8, ...
    for (int m = w; m < 64; m += 8) {
      int gm = (int)arow0 + half * 64 + m;
      int beg = offs[gm];
      int end = offs[gm + 1];
      if (beg == end) continue;
      float2 pv = *(const float2*)&ep[m * EPS + lane * 2];
      for (int p = beg; p < end; ++p) {
        int t = perm[p];
        int c = cid[t];
        float2 hv = *(const float2*)&Hc[(size_t)c * NDIM + brow0 + lane * 2];
        nt_store_f2(&out[(size_t)t * NDIM + brow0 + lane * 2],
                    fmaxf(pv.x + hv.x, 0.f), fmaxf(pv.y + hv.y, 0.f));
      }
    }
    __syncthreads();
  }
}

extern "C" void kernel_launch(void* const* d_in, const int* in_sizes, int n_in,
                              void* d_out, int out_size, void* d_ws, size_t ws_size,
                              hipStream_t stream) {
  (void)in_sizes; (void)n_in; (void)out_size;
  const float* word_emb = (const float*)d_in[0];
  const int*   char_ids = (const int*)d_in[1];
  const int*   word_ids = (const int*)d_in[2];
  const float* E        = (const float*)d_in[3];
  const float* W_ih     = (const float*)d_in[4];
  const float* b_ih     = (const float*)d_in[5];
  const float* b_hh     = (const float*)d_in[6];
  const float* W_lin    = (const float*)d_in[7];
  const float* b_lin    = (const float*)d_in[8];
  float* out = (float*)d_out;
  char* ws = (char*)d_ws;

  size_t o = 0;
  auto alloc = [&](size_t b) { size_t r = o; o = (o + b + 255) & ~(size_t)255; return r; };
  size_t oHc   = alloc((size_t)NEMB * NDIM * 4);
  size_t oH    = alloc((size_t)NEMB * HID * 4);
  size_t oBh   = alloc((size_t)NDIM * KDIM * 2);
  size_t oBl   = alloc((size_t)NDIM * KDIM * 2);
  size_t oCnt  = alloc((size_t)NWORDS * 4);
  size_t oOffs = alloc((size_t)(NWORDS + 1) * 4);
  size_t oCur  = alloc((size_t)NWORDS * 4);
  size_t oPerm = alloc((size_t)T_TOTAL * 4);
  size_t oAh   = alloc((size_t)NWORDS * KDIM * 2);
  size_t oAl   = alloc((size_t)NWORDS * KDIM * 2);
  size_t needA = o;

  float* Hc          = (float*)(ws + oHc);
  float* hbuf        = (float*)(ws + oH);
  unsigned short* Bh = (unsigned short*)(ws + oBh);
  unsigned short* Bl = (unsigned short*)(ws + oBl);
  int* cnt   = (int*)(ws + oCnt);
  int* offsp = (int*)(ws + oOffs);
  int* cur   = (int*)(ws + oCur);
  int* perm  = (int*)(ws + oPerm);
  unsigned short* Ah = (unsigned short*)(ws + oAh);
  unsigned short* Al = (unsigned short*)(ws + oAl);

  bool preconv = (ws_size >= needA);

  // inverted index word -> char positions
  k_zero<<<(NWORDS + 255) / 256, 256, 0, stream>>>(cnt, NWORDS);
  k_hist<<<T_TOTAL / 256, 256, 0, stream>>>(word_ids, cnt);
  k_scan<<<1, 1024, 0, stream>>>(cnt, offsp, cur);
  k_scatter<<<T_TOTAL / 256, 256, 0, stream>>>(word_ids, cur, perm);

  // LSTM-branch table + W1 split
  k_prep_h<<<NEMB, 256, 0, stream>>>(E, W_ih, b_ih, b_hh, hbuf);
  k_prep_hc2<<<NEMB * 4, 256, 0, stream>>>(hbuf, W_lin, b_lin, Hc);
  k_conv<<<(NDIM * KDIM / 4) / 256, 256, 0, stream>>>(W_lin, 1536L, Bh, Bl);

  int grid = (NWORDS / BM) * (NDIM / BN);  // 2048
  if (preconv) {
    k_conv<<<((size_t)NWORDS * KDIM / 4) / 256, 256, 0, stream>>>(word_emb, 1024L, Ah, Al);
    k_gemm_scatter<true><<<grid, 512, 0, stream>>>(
        word_emb, Ah, Al, Bh, Bl, Hc, offsp, perm, char_ids, out);
  } else {
    k_gemm_scatter<false><<<grid, 512, 0, stream>>>(
        word_emb, Ah, Al, Bh, Bl, Hc, offsp, perm, char_ids, out);
  }
}

// Round 5
// 559.717 us; speedup vs baseline: 1.2666x; 1.0119x over previous
//
#include <hip/hip_runtime.h>
#include <cstdint>
#include <cstddef>

#define T_TOTAL   131072
#define NWORDS    32768
#define WDIM      1024
#define CDIM      256
#define HID       512
#define NEMB      40
#define KDIM      1024
#define NDIM      1024

#define BM 128
#define BN 128
#define BK 32
#define NK (KDIM / BK)
#define EPS 132   // epilogue LDS row stride (floats): 528B -> bank-even
#define HCOFF 33792  // byte offset of Hc slice in smem (after 64*EPS*4)

typedef __attribute__((ext_vector_type(8))) short bf16x8;
typedef __attribute__((ext_vector_type(4))) float f32x4;
typedef __attribute__((ext_vector_type(4))) unsigned short u16x4;

__device__ __forceinline__ unsigned short f2bf(float x) {
  union { float f; unsigned int u; } v; v.f = x;
  unsigned int r = v.u + 0x7fffu + ((v.u >> 16) & 1u);   // RNE
  return (unsigned short)(r >> 16);
}
__device__ __forceinline__ float bf2f(unsigned short b) {
  union { float f; unsigned int u; } v; v.u = ((unsigned int)b) << 16;
  return v.f;
}

__device__ __forceinline__ void gld16(const void* src, void* lds) {
  __builtin_amdgcn_global_load_lds(
      (const __attribute__((address_space(1))) unsigned int*)src,
      (__attribute__((address_space(3))) unsigned int*)lds, 16, 0, 0);
}

__device__ __forceinline__ void nt_store_f2(float* p, float a, float b) {
  union { float f[2]; unsigned long long u; } v;
  v.f[0] = a; v.f[1] = b;
  __builtin_nontemporal_store(v.u, (unsigned long long*)p);
}

// ---------------- index build ----------------
__global__ __launch_bounds__(256) void k_zero(int* __restrict__ p, int n) {
  int i = blockIdx.x * 256 + threadIdx.x;
  if (i < n) p[i] = 0;
}

__global__ __launch_bounds__(256) void k_hist(const int* __restrict__ wid,
                                              int* __restrict__ cnt) {
  int i = blockIdx.x * 256 + threadIdx.x;
  atomicAdd(&cnt[wid[i]], 1);
}

__global__ __launch_bounds__(1024) void k_scan(const int* __restrict__ cnt,
                                               int* __restrict__ offs,
                                               int* __restrict__ cur) {
  __shared__ int ps[1024];
  int tid = threadIdx.x;
  int base = tid * 32;
  int s = 0;
  for (int i = 0; i < 32; ++i) s += cnt[base + i];
  ps[tid] = s;
  __syncthreads();
  for (int d = 1; d < 1024; d <<= 1) {
    int add = (tid >= d) ? ps[tid - d] : 0;
    __syncthreads();
    ps[tid] += add;
    __syncthreads();
  }
  int run = (tid > 0) ? ps[tid - 1] : 0;
  for (int i = 0; i < 32; ++i) {
    int v = cnt[base + i];
    offs[base + i] = run;
    cur[base + i] = run;
    run += v;
  }
  if (tid == 1023) offs[NWORDS] = run;
}

// pack char id into perm entry: perm[p] = (t << 6) | cid[t]   (t<2^17, cid<64)
__global__ __launch_bounds__(256) void k_scatter(const int* __restrict__ wid,
                                                 const int* __restrict__ cidv,
                                                 int* __restrict__ cur,
                                                 unsigned int* __restrict__ perm) {
  int i = blockIdx.x * 256 + threadIdx.x;
  int w = wid[i];
  int p = atomicAdd(&cur[w], 1);
  perm[p] = ((unsigned int)i << 6) | (unsigned int)cidv[i];
}

// ---------------- LSTM h table: 40 x 512 ----------------
__global__ __launch_bounds__(256) void k_prep_h(const float* __restrict__ E,
                                                const float* __restrict__ W_ih,
                                                const float* __restrict__ b_ih,
                                                const float* __restrict__ b_hh,
                                                float* __restrict__ h) {
  int e = blockIdx.x;
  int tid = threadIdx.x;
  __shared__ float x[CDIM];
  x[tid] = E[e * CDIM + tid];
  __syncthreads();
  const float4* xv = (const float4*)x;
#pragma unroll
  for (int rep = 0; rep < 2; ++rep) {
    int j = rep * 256 + tid;                       // j in [0,512)
    float si = b_ih[j] + b_hh[j];
    float sg = b_ih[1024 + j] + b_hh[1024 + j];
    float so = b_ih[1536 + j] + b_hh[1536 + j];
    const float4* wi = (const float4*)&W_ih[(size_t)j * CDIM];
    const float4* wg = (const float4*)&W_ih[(size_t)(1024 + j) * CDIM];
    const float4* wo = (const float4*)&W_ih[(size_t)(1536 + j) * CDIM];
    for (int k = 0; k < CDIM / 4; ++k) {
      float4 d = xv[k];
      float4 a = wi[k]; si += a.x*d.x + a.y*d.y + a.z*d.z + a.w*d.w;
      float4 b = wg[k]; sg += b.x*d.x + b.y*d.y + b.z*d.z + b.w*d.w;
      float4 c = wo[k]; so += c.x*d.x + c.y*d.y + c.z*d.z + c.w*d.w;
    }
    float iv = 1.f / (1.f + expf(-si));
    float cv = iv * tanhf(sg);
    float ov = 1.f / (1.f + expf(-so));
    h[e * HID + j] = ov * tanhf(cv);
  }
}

// ---------------- Hc table: 40 x 1024 = W_lin[:,1024:] @ h + b_lin ----------------
__global__ __launch_bounds__(256) void k_prep_hc2(const float* __restrict__ h,
                                                  const float* __restrict__ W_lin,
                                                  const float* __restrict__ b_lin,
                                                  float* __restrict__ Hc) {
  int e = blockIdx.x >> 2;
  int chunk = blockIdx.x & 3;
  int tid = threadIdx.x;
  __shared__ float hs[HID];
  hs[tid] = h[e * HID + tid];
  hs[256 + tid] = h[e * HID + 256 + tid];
  __syncthreads();
  int n = chunk * 256 + tid;
  float s = b_lin[n];
  const float4* wl = (const float4*)&W_lin[(size_t)n * 1536 + 1024];
  const float4* hv = (const float4*)hs;
  for (int k = 0; k < HID / 4; ++k) {
    float4 a = wl[k], b = hv[k];
    s += a.x*b.x + a.y*b.y + a.z*b.z + a.w*b.w;
  }
  Hc[e * NDIM + n] = s;
}

// ---------------- fp32 -> (hi,lo) bf16 split, cols [0,1024) of a row-major mat ----------------
__global__ __launch_bounds__(256) void k_conv(const float* __restrict__ src, long ld,
                                              unsigned short* __restrict__ hi,
                                              unsigned short* __restrict__ lo) {
  long idx = ((long)blockIdx.x * 256 + threadIdx.x) * 4;
  long r = idx >> 10;
  int c = (int)(idx & 1023);
  const float4 v = *(const float4*)&src[r * ld + c];
  unsigned short h0 = f2bf(v.x), h1 = f2bf(v.y), h2 = f2bf(v.z), h3 = f2bf(v.w);
  u16x4 H = {h0, h1, h2, h3};
  u16x4 L = {f2bf(v.x - bf2f(h0)), f2bf(v.y - bf2f(h1)),
             f2bf(v.z - bf2f(h2)), f2bf(v.w - bf2f(h3))};
  *(u16x4*)&hi[idx] = H;
  *(u16x4*)&lo[idx] = L;
}

// ---------------- main GEMM (dedup'd words) + coalesced scatter epilogue ----------------
// P[m][n] = sum_k we[m][k] * W_lin[n][k]  via split-bf16 3-MFMA emulation.
// 256 threads / 4 waves (2x2 grid, wave tile 64x64 -> 128 B/lane/iter LDS reads),
// 2 x 32KB LDS double-buffer, counted-vmcnt pipeline, raw s_barrier.
// XOR slot-swizzle (slot' = slot ^ ((row>>1)&3)) on the GLOBAL source (LDS dest
// linear, required by global_load_lds) and on the fragment reads -> 0 conflicts.
// Epilogue: P tile + 40x128 Hc slice staged in LDS; packed perm (t<<6|cid);
// wave-cooperative 512B nontemporal row stores.
template <bool PRECONV>
__global__ __launch_bounds__(256, 2) void k_gemm_scatter(
    const float* __restrict__ Af,
    const unsigned short* __restrict__ Ah, const unsigned short* __restrict__ Al,
    const unsigned short* __restrict__ Bh, const unsigned short* __restrict__ Bl,
    const float* __restrict__ Hc, const int* __restrict__ offs,
    const unsigned int* __restrict__ perm,
    float* __restrict__ out) {
  // buf = smem + b*32768: [A-hi 8K][A-lo 8K][B-hi 8K][B-lo 8K]
  // Epilogue overlay: ep = smem[0,33792), hs = smem[33792,54272)
  __shared__ __align__(16) char smem[65536];

  int nwg = gridDim.x;
  int bid = blockIdx.x;
  int cpx = nwg >> 3;                       // XCD-contiguous swizzle (nwg % 8 == 0)
  int swz = (bid & 7) * cpx + (bid >> 3);
  int bn = swz & 7;                         // NDIM/BN == 8
  int bm = swz >> 3;

  int tid = threadIdx.x;
  int lane = tid & 63;
  int w = tid >> 6;                         // 0..3
  int wr = w >> 1, wc = w & 1;              // 2 x 2 wave grid; wave tile 64x64
  int fr = lane & 15, fq = lane >> 4;

  size_t arow0 = (size_t)bm * BM;
  size_t brow0 = (size_t)bn * BN;

  f32x4 acc[4][4];
#pragma unroll
  for (int i = 0; i < 4; ++i)
#pragma unroll
    for (int j = 0; j < 4; ++j) acc[i][j] = (f32x4)0.0f;

  if (PRECONV) {
    // ---- loop-invariant staging descriptors (2 x 16B per thread per sub-array)
    size_t aSrc[2], bSrc[2];
    int ldsOff[2];
#pragma unroll
    for (int is = 0; is < 2; ++is) {
      int off = is * 4096 + tid * 16;
      int r = off >> 6;                     // row 0..127
      int sp = (off >> 4) & 3;              // physical 16B slot in 64B row
      int colE = ((sp ^ ((r >> 1) & 3)) << 3);  // swizzled source col (bf16 elems)
      aSrc[is] = (arow0 + r) * KDIM + colE;
      bSrc[is] = (brow0 + r) * KDIM + colE;
      ldsOff[is] = is * 4096 + w * 1024;    // wave-uniform LDS base
    }
    // ---- loop-invariant fragment read offsets (swizzled)
    int aOff[4], bOff[4];
#pragma unroll
    for (int mi = 0; mi < 4; ++mi) {
      int row = wr * 64 + mi * 16 + fr;
      aOff[mi] = row * 64 + ((fq ^ ((row >> 1) & 3)) << 4);
    }
#pragma unroll
    for (int ni = 0; ni < 4; ++ni) {
      int row = wc * 64 + ni * 16 + fr;
      bOff[ni] = row * 64 + ((fq ^ ((row >> 1) & 3)) << 4);
    }

    auto STAGE = [&](int buf, int k0) {       // 8 gld16 per thread
      char* b = smem + buf * 32768;
#pragma unroll
      for (int is = 0; is < 2; ++is) {
        gld16(Ah + aSrc[is] + k0, b + ldsOff[is]);
        gld16(Al + aSrc[is] + k0, b + 8192 + ldsOff[is]);
        gld16(Bh + bSrc[is] + k0, b + 16384 + ldsOff[is]);
        gld16(Bl + bSrc[is] + k0, b + 24576 + ldsOff[is]);
      }
    };

    STAGE(0, 0);                            // 8 loads in flight
    for (int t = 0; t < NK; ++t) {
      char* bufc = smem + (t & 1) * 32768;
      if (t + 1 < NK) {
        STAGE((t + 1) & 1, (t + 1) * BK);   // +8 -> 16 in flight
        asm volatile("s_waitcnt vmcnt(8)" ::: "memory");  // tile t landed, t+1 flying
      } else {
        asm volatile("s_waitcnt vmcnt(0)" ::: "memory");
      }
      __builtin_amdgcn_s_barrier();
      __builtin_amdgcn_sched_barrier(0);

      bf16x8 fah[4], fal[4], fbh[4], fbl[4];
#pragma unroll
      for (int ni = 0; ni < 4; ++ni) {
        fbh[ni] = *(const bf16x8*)(bufc + 16384 + bOff[ni]);
        fbl[ni] = *(const bf16x8*)(bufc + 24576 + bOff[ni]);
      }
#pragma unroll
      for (int mi = 0; mi < 4; ++mi) {
        fah[mi] = *(const bf16x8*)(bufc + aOff[mi]);
        fal[mi] = *(const bf16x8*)(bufc + 8192 + aOff[mi]);
      }
      __builtin_amdgcn_s_setprio(1);
#pragma unroll
      for (int mi = 0; mi < 4; ++mi)
#pragma unroll
        for (int ni = 0; ni < 4; ++ni) {
          acc[mi][ni] = __builtin_amdgcn_mfma_f32_16x16x32_bf16(fah[mi], fbh[ni], acc[mi][ni], 0, 0, 0);
          acc[mi][ni] = __builtin_amdgcn_mfma_f32_16x16x32_bf16(fah[mi], fbl[ni], acc[mi][ni], 0, 0, 0);
          acc[mi][ni] = __builtin_amdgcn_mfma_f32_16x16x32_bf16(fal[mi], fbh[ni], acc[mi][ni], 0, 0, 0);
        }
      __builtin_amdgcn_s_setprio(0);
      __builtin_amdgcn_sched_barrier(0);    // keep ds_reads above this barrier
      __builtin_amdgcn_s_barrier();         // protect buf t from tile t+2 staging
    }
  } else {
    // Fallback: single-buffer, split A from fp32 in-kernel (compat path)
    char* sA  = smem;                       // fp32 128x32, 8-slot swizzled rows (16 KB)
    char* sBh = smem + 16384;
    char* sBl = smem + 24576;
    int kb = fq * 8;
    for (int k0 = 0; k0 < KDIM; k0 += BK) {
#pragma unroll
      for (int is = 0; is < 2; ++is) {
        int off = is * 4096 + tid * 16;
        int r = off >> 6;
        int col = (off & 63) >> 1;
        int ldsoff = is * 4096 + w * 1024;
        gld16(Bh + (brow0 + r) * KDIM + k0 + col, sBh + ldsoff);
        gld16(Bl + (brow0 + r) * KDIM + k0 + col, sBl + ldsoff);
      }
#pragma unroll
      for (int is = 0; is < 4; ++is) {
        int off = is * 4096 + tid * 16;
        int r = off >> 7;
        int sl = (off >> 4) & 7;
        int col = ((sl ^ (r & 7)) << 2);    // floats
        int ldsoff = is * 4096 + w * 1024;
        gld16(Af + (arow0 + r) * KDIM + k0 + col, sA + ldsoff);
      }
      __syncthreads();

      bf16x8 fah[4], fal[4], fbh[4], fbl[4];
#pragma unroll
      for (int ni = 0; ni < 4; ++ni) {
        int row = wc * 64 + ni * 16 + fr;
        fbh[ni] = *(const bf16x8*)(sBh + row * 64 + (kb << 1));
        fbl[ni] = *(const bf16x8*)(sBl + row * 64 + (kb << 1));
      }
#pragma unroll
      for (int mi = 0; mi < 4; ++mi) {
        int row = wr * 64 + mi * 16 + fr;
        int s1 = (kb >> 2) ^ (row & 7);
        int s2 = ((kb >> 2) + 1) ^ (row & 7);
        float4 v1 = *(const float4*)(sA + row * 128 + s1 * 16);
        float4 v2 = *(const float4*)(sA + row * 128 + s2 * 16);
        float f[8] = {v1.x, v1.y, v1.z, v1.w, v2.x, v2.y, v2.z, v2.w};
        union { bf16x8 v; unsigned short u[8]; } H, L;
#pragma unroll
        for (int q = 0; q < 8; ++q) {
          unsigned short hq = f2bf(f[q]);
          H.u[q] = hq;
          L.u[q] = f2bf(f[q] - bf2f(hq));
        }
        fah[mi] = H.v;
        fal[mi] = L.v;
      }
#pragma unroll
      for (int mi = 0; mi < 4; ++mi)
#pragma unroll
        for (int ni = 0; ni < 4; ++ni) {
          acc[mi][ni] = __builtin_amdgcn_mfma_f32_16x16x32_bf16(fah[mi], fbh[ni], acc[mi][ni], 0, 0, 0);
          acc[mi][ni] = __builtin_amdgcn_mfma_f32_16x16x32_bf16(fah[mi], fbl[ni], acc[mi][ni], 0, 0, 0);
          acc[mi][ni] = __builtin_amdgcn_mfma_f32_16x16x32_bf16(fal[mi], fbh[ni], acc[mi][ni], 0, 0, 0);
        }
      __syncthreads();
    }
  }

  // ---- epilogue ----
  // C/D frag layout: row = wr*64 + mi*16 + fq*4 + j, col = wc*64 + ni*16 + fr
  float* ep = (float*)smem;
  float* hs = (float*)(smem + HCOFF);       // [40][128] Hc slice for this bn
  __syncthreads();                          // drain before overlaying staging buffers
  // stage Hc slice (20 KB, coalesced float4)
  for (int i = tid; i < NEMB * 32; i += 256) {
    int rr = i >> 5;
    int cc = (i & 31) << 2;
    *(float4*)&hs[rr * 128 + cc] = *(const float4*)&Hc[(size_t)rr * NDIM + brow0 + cc];
  }
#pragma unroll
  for (int half = 0; half < 2; ++half) {
    if (wr == half) {
#pragma unroll
      for (int mi = 0; mi < 4; ++mi)
#pragma unroll
        for (int ni = 0; ni < 4; ++ni)
#pragma unroll
          for (int j = 0; j < 4; ++j) {
            int r = mi * 16 + fq * 4 + j;
            int c = wc * 64 + ni * 16 + fr;
            ep[r * EPS + c] = acc[mi][ni][j];
          }
    }
    __syncthreads();
    // rows [half*64, half*64+64): wave w handles rows w, w+4, ...
    for (int m = w; m < 64; m += 4) {
      int gm = (int)arow0 + half * 64 + m;
      int beg = offs[gm];
      int end = offs[gm + 1];
      if (beg == end) continue;
      float2 pv = *(const float2*)&ep[m * EPS + lane * 2];
      unsigned int v = perm[beg];
      for (int p = beg; p < end; ++p) {
        int pn = (p + 1 < end) ? p + 1 : p;
        unsigned int vn = perm[pn];         // prefetch next (hides L2 latency)
        int t = (int)(v >> 6);
        int c = (int)(v & 63u);
        float2 hv = *(const float2*)&hs[c * 128 + lane * 2];
        nt_store_f2(&out[(size_t)t * NDIM + brow0 + lane * 2],
                    fmaxf(pv.x + hv.x, 0.f), fmaxf(pv.y + hv.y, 0.f));
        v = vn;
      }
    }
    __syncthreads();
  }
}

extern "C" void kernel_launch(void* const* d_in, const int* in_sizes, int n_in,
                              void* d_out, int out_size, void* d_ws, size_t ws_size,
                              hipStream_t stream) {
  (void)in_sizes; (void)n_in; (void)out_size;
  const float* word_emb = (const float*)d_in[0];
  const int*   char_ids = (const int*)d_in[1];
  const int*   word_ids = (const int*)d_in[2];
  const float* E        = (const float*)d_in[3];
  const float* W_ih     = (const float*)d_in[4];
  const float* b_ih     = (const float*)d_in[5];
  const float* b_hh     = (const float*)d_in[6];
  const float* W_lin    = (const float*)d_in[7];
  const float* b_lin    = (const float*)d_in[8];
  float* out = (float*)d_out;
  char* ws = (char*)d_ws;

  size_t o = 0;
  auto alloc = [&](size_t b) { size_t r = o; o = (o + b + 255) & ~(size_t)255; return r; };
  size_t oHc   = alloc((size_t)NEMB * NDIM * 4);
  size_t oH    = alloc((size_t)NEMB * HID * 4);
  size_t oBh   = alloc((size_t)NDIM * KDIM * 2);
  size_t oBl   = alloc((size_t)NDIM * KDIM * 2);
  size_t oCnt  = alloc((size_t)NWORDS * 4);
  size_t oOffs = alloc((size_t)(NWORDS + 1) * 4);
  size_t oCur  = alloc((size_t)NWORDS * 4);
  size_t oPerm = alloc((size_t)T_TOTAL * 4);
  size_t oAh   = alloc((size_t)NWORDS * KDIM * 2);
  size_t oAl   = alloc((size_t)NWORDS * KDIM * 2);
  size_t needA = o;

  float* Hc          = (float*)(ws + oHc);
  float* hbuf        = (float*)(ws + oH);
  unsigned short* Bh = (unsigned short*)(ws + oBh);
  unsigned short* Bl = (unsigned short*)(ws + oBl);
  int* cnt   = (int*)(ws + oCnt);
  int* offsp = (int*)(ws + oOffs);
  int* cur   = (int*)(ws + oCur);
  unsigned int* perm = (unsigned int*)(ws + oPerm);
  unsigned short* Ah = (unsigned short*)(ws + oAh);
  unsigned short* Al = (unsigned short*)(ws + oAl);

  bool preconv = (ws_size >= needA);

  // inverted index word -> char positions (cid packed into perm)
  k_zero<<<(NWORDS + 255) / 256, 256, 0, stream>>>(cnt, NWORDS);
  k_hist<<<T_TOTAL / 256, 256, 0, stream>>>(word_ids, cnt);
  k_scan<<<1, 1024, 0, stream>>>(cnt, offsp, cur);
  k_scatter<<<T_TOTAL / 256, 256, 0, stream>>>(word_ids, char_ids, cur, perm);

  // LSTM-branch table + W1 split
  k_prep_h<<<NEMB, 256, 0, stream>>>(E, W_ih, b_ih, b_hh, hbuf);
  k_prep_hc2<<<NEMB * 4, 256, 0, stream>>>(hbuf, W_lin, b_lin, Hc);
  k_conv<<<(NDIM * KDIM / 4) / 256, 256, 0, stream>>>(W_lin, 1536L, Bh, Bl);

  int grid = (NWORDS / BM) * (NDIM / BN);  // 2048
  if (preconv) {
    k_conv<<<((size_t)NWORDS * KDIM / 4) / 256, 256, 0, stream>>>(word_emb, 1024L, Ah, Al);
    k_gemm_scatter<true><<<grid, 256, 0, stream>>>(
        word_emb, Ah, Al, Bh, Bl, Hc, offsp, perm, out);
  } else {
    k_gemm_scatter<false><<<grid, 256, 0, stream>>>(
        word_emb, Ah, Al, Bh, Bl, Hc, offsp, perm, out);
  }
}

// Round 6
// 516.078 us; speedup vs baseline: 1.3737x; 1.0846x over previous
//
#include <hip/hip_runtime.h>
#include <cstdint>
#include <cstddef>

#define T_TOTAL   131072
#define NWORDS    32768
#define WDIM      1024
#define CDIM      256
#define HID       512
#define NEMB      40
#define KDIM      1024
#define NDIM      1024

#define BM 128
#define BN 128
#define BK 32
#define NK (KDIM / BK)
#define EPS 132   // epilogue LDS row stride (floats): 528B -> bank-even
#define HCOFF 33792

typedef __attribute__((ext_vector_type(8))) short bf16x8;
typedef __attribute__((ext_vector_type(4))) float f32x4;
typedef __attribute__((ext_vector_type(4))) unsigned short u16x4;

__device__ __forceinline__ unsigned short f2bf(float x) {
  union { float f; unsigned int u; } v; v.f = x;
  unsigned int r = v.u + 0x7fffu + ((v.u >> 16) & 1u);   // RNE
  return (unsigned short)(r >> 16);
}
__device__ __forceinline__ float bf2f(unsigned short b) {
  union { float f; unsigned int u; } v; v.u = ((unsigned int)b) << 16;
  return v.f;
}

__device__ __forceinline__ void gld16(const void* src, void* lds) {
  __builtin_amdgcn_global_load_lds(
      (const __attribute__((address_space(1))) unsigned int*)src,
      (__attribute__((address_space(3))) unsigned int*)lds, 16, 0, 0);
}

__device__ __forceinline__ void nt_store_f2(float* p, float a, float b) {
  union { float f[2]; unsigned long long u; } v;
  v.f[0] = a; v.f[1] = b;
  __builtin_nontemporal_store(v.u, (unsigned long long*)p);
}

// ---------------- index build (Plan C only) ----------------
__global__ __launch_bounds__(256) void k_zero(int* __restrict__ p, int n) {
  int i = blockIdx.x * 256 + threadIdx.x;
  if (i < n) p[i] = 0;
}

__global__ __launch_bounds__(256) void k_hist(const int* __restrict__ wid,
                                              int* __restrict__ cnt) {
  int i = blockIdx.x * 256 + threadIdx.x;
  atomicAdd(&cnt[wid[i]], 1);
}

__global__ __launch_bounds__(1024) void k_scan(const int* __restrict__ cnt,
                                               int* __restrict__ offs,
                                               int* __restrict__ cur) {
  __shared__ int ps[1024];
  int tid = threadIdx.x;
  int base = tid * 32;
  int s = 0;
  for (int i = 0; i < 32; ++i) s += cnt[base + i];
  ps[tid] = s;
  __syncthreads();
  for (int d = 1; d < 1024; d <<= 1) {
    int add = (tid >= d) ? ps[tid - d] : 0;
    __syncthreads();
    ps[tid] += add;
    __syncthreads();
  }
  int run = (tid > 0) ? ps[tid - 1] : 0;
  for (int i = 0; i < 32; ++i) {
    int v = cnt[base + i];
    offs[base + i] = run;
    cur[base + i] = run;
    run += v;
  }
  if (tid == 1023) offs[NWORDS] = run;
}

__global__ __launch_bounds__(256) void k_scatter(const int* __restrict__ wid,
                                                 const int* __restrict__ cidv,
                                                 int* __restrict__ cur,
                                                 unsigned int* __restrict__ perm) {
  int i = blockIdx.x * 256 + threadIdx.x;
  int w = wid[i];
  int p = atomicAdd(&cur[w], 1);
  perm[p] = ((unsigned int)i << 6) | (unsigned int)cidv[i];
}

// ---------------- LSTM h table: 40 x 512 ----------------
__global__ __launch_bounds__(256) void k_prep_h(const float* __restrict__ E,
                                                const float* __restrict__ W_ih,
                                                const float* __restrict__ b_ih,
                                                const float* __restrict__ b_hh,
                                                float* __restrict__ h) {
  int e = blockIdx.x;
  int tid = threadIdx.x;
  __shared__ float x[CDIM];
  x[tid] = E[e * CDIM + tid];
  __syncthreads();
  const float4* xv = (const float4*)x;
#pragma unroll
  for (int rep = 0; rep < 2; ++rep) {
    int j = rep * 256 + tid;
    float si = b_ih[j] + b_hh[j];
    float sg = b_ih[1024 + j] + b_hh[1024 + j];
    float so = b_ih[1536 + j] + b_hh[1536 + j];
    const float4* wi = (const float4*)&W_ih[(size_t)j * CDIM];
    const float4* wg = (const float4*)&W_ih[(size_t)(1024 + j) * CDIM];
    const float4* wo = (const float4*)&W_ih[(size_t)(1536 + j) * CDIM];
    for (int k = 0; k < CDIM / 4; ++k) {
      float4 d = xv[k];
      float4 a = wi[k]; si += a.x*d.x + a.y*d.y + a.z*d.z + a.w*d.w;
      float4 b = wg[k]; sg += b.x*d.x + b.y*d.y + b.z*d.z + b.w*d.w;
      float4 c = wo[k]; so += c.x*d.x + c.y*d.y + c.z*d.z + c.w*d.w;
    }
    float iv = 1.f / (1.f + expf(-si));
    float cv = iv * tanhf(sg);
    float ov = 1.f / (1.f + expf(-so));
    h[e * HID + j] = ov * tanhf(cv);
  }
}

// ---------------- Hc table: 40 x 1024 = W_lin[:,1024:] @ h + b_lin ----------------
__global__ __launch_bounds__(256) void k_prep_hc2(const float* __restrict__ h,
                                                  const float* __restrict__ W_lin,
                                                  const float* __restrict__ b_lin,
                                                  float* __restrict__ Hc) {
  int e = blockIdx.x >> 2;
  int chunk = blockIdx.x & 3;
  int tid = threadIdx.x;
  __shared__ float hs[HID];
  hs[tid] = h[e * HID + tid];
  hs[256 + tid] = h[e * HID + 256 + tid];
  __syncthreads();
  int n = chunk * 256 + tid;
  float s = b_lin[n];
  const float4* wl = (const float4*)&W_lin[(size_t)n * 1536 + 1024];
  const float4* hv = (const float4*)hs;
  for (int k = 0; k < HID / 4; ++k) {
    float4 a = wl[k], b = hv[k];
    s += a.x*b.x + a.y*b.y + a.z*b.z + a.w*b.w;
  }
  Hc[e * NDIM + n] = s;
}

// ---------------- fp32 -> (hi,lo) bf16 split ----------------
__global__ __launch_bounds__(256) void k_conv(const float* __restrict__ src, long ld,
                                              unsigned short* __restrict__ hi,
                                              unsigned short* __restrict__ lo) {
  long idx = ((long)blockIdx.x * 256 + threadIdx.x) * 4;
  long r = idx >> 10;
  int c = (int)(idx & 1023);
  const float4 v = *(const float4*)&src[r * ld + c];
  unsigned short h0 = f2bf(v.x), h1 = f2bf(v.y), h2 = f2bf(v.z), h3 = f2bf(v.w);
  u16x4 H = {h0, h1, h2, h3};
  u16x4 L = {f2bf(v.x - bf2f(h0)), f2bf(v.y - bf2f(h1)),
             f2bf(v.z - bf2f(h2)), f2bf(v.w - bf2f(h3))};
  *(u16x4*)&hi[idx] = H;
  *(u16x4*)&lo[idx] = L;
}

// ---------------- GEMM (dedup'd words) -> P[32768][1024] ----------------
// P[m][n] = sum_k we[m][k] * W_lin[n][k] via split-bf16 3-MFMA emulation.
// 256 thr / 4 waves (2x2, wave tile 64x64), 2 x 32KB dbuf, counted vmcnt.
// PRECONV=true : A pre-split (Ah/Al bf16), XOR slot-swizzle both sides.
// PRECONV=false: A staged fp32 (16KB/tile, 8-slot XOR swizzle), split in-kernel.
template <bool PRECONV>
__global__ __launch_bounds__(256, 2) void k_gemm_p(
    const float* __restrict__ Af,
    const unsigned short* __restrict__ Ah, const unsigned short* __restrict__ Al,
    const unsigned short* __restrict__ Bh, const unsigned short* __restrict__ Bl,
    float* __restrict__ P) {
  __shared__ __align__(16) char smem[65536];

  int nwg = gridDim.x;
  int bid = blockIdx.x;
  int cpx = nwg >> 3;
  int swz = (bid & 7) * cpx + (bid >> 3);
  int bn = swz & 7;
  int bm = swz >> 3;

  int tid = threadIdx.x;
  int lane = tid & 63;
  int w = tid >> 6;
  int wr = w >> 1, wc = w & 1;
  int fr = lane & 15, fq = lane >> 4;

  size_t arow0 = (size_t)bm * BM;
  size_t brow0 = (size_t)bn * BN;

  f32x4 acc[4][4];
#pragma unroll
  for (int i = 0; i < 4; ++i)
#pragma unroll
    for (int j = 0; j < 4; ++j) acc[i][j] = (f32x4)0.0f;

  // B fragment read offsets (swizzled), shared by both paths
  int bOff[4];
#pragma unroll
  for (int ni = 0; ni < 4; ++ni) {
    int row = wc * 64 + ni * 16 + fr;
    bOff[ni] = row * 64 + ((fq ^ ((row >> 1) & 3)) << 4);
  }
  // B staging descriptors (2 x 16B per thread), bf16 64B rows, 4-slot swizzle
  size_t bS[2]; int bL[2];
#pragma unroll
  for (int is = 0; is < 2; ++is) {
    int off = is * 4096 + tid * 16;
    int r = off >> 6;
    int sp = (off >> 4) & 3;
    int colE = ((sp ^ ((r >> 1) & 3)) << 3);
    bS[is] = (brow0 + r) * KDIM + colE;
    bL[is] = is * 4096 + w * 1024;
  }

  if (PRECONV) {
    size_t aS[2];
#pragma unroll
    for (int is = 0; is < 2; ++is) {
      int off = is * 4096 + tid * 16;
      int r = off >> 6;
      int sp = (off >> 4) & 3;
      int colE = ((sp ^ ((r >> 1) & 3)) << 3);
      aS[is] = (arow0 + r) * KDIM + colE;
    }
    int aOff[4];
#pragma unroll
    for (int mi = 0; mi < 4; ++mi) {
      int row = wr * 64 + mi * 16 + fr;
      aOff[mi] = row * 64 + ((fq ^ ((row >> 1) & 3)) << 4);
    }

    auto STAGE = [&](int buf, int k0) {     // 8 gld16 / thread
      char* b = smem + buf * 32768;
#pragma unroll
      for (int is = 0; is < 2; ++is) {
        gld16(Ah + aS[is] + k0, b + bL[is]);
        gld16(Al + aS[is] + k0, b + 8192 + bL[is]);
        gld16(Bh + bS[is] + k0, b + 16384 + bL[is]);
        gld16(Bl + bS[is] + k0, b + 24576 + bL[is]);
      }
    };

    STAGE(0, 0);
    for (int t = 0; t < NK; ++t) {
      char* bufc = smem + (t & 1) * 32768;
      if (t + 1 < NK) {
        STAGE((t + 1) & 1, (t + 1) * BK);
        asm volatile("s_waitcnt vmcnt(8)" ::: "memory");
      } else {
        asm volatile("s_waitcnt vmcnt(0)" ::: "memory");
      }
      __builtin_amdgcn_s_barrier();
      __builtin_amdgcn_sched_barrier(0);

      bf16x8 fah[4], fal[4], fbh[4], fbl[4];
#pragma unroll
      for (int ni = 0; ni < 4; ++ni) {
        fbh[ni] = *(const bf16x8*)(bufc + 16384 + bOff[ni]);
        fbl[ni] = *(const bf16x8*)(bufc + 24576 + bOff[ni]);
      }
#pragma unroll
      for (int mi = 0; mi < 4; ++mi) {
        fah[mi] = *(const bf16x8*)(bufc + aOff[mi]);
        fal[mi] = *(const bf16x8*)(bufc + 8192 + aOff[mi]);
      }
      __builtin_amdgcn_s_setprio(1);
#pragma unroll
      for (int mi = 0; mi < 4; ++mi)
#pragma unroll
        for (int ni = 0; ni < 4; ++ni) {
          acc[mi][ni] = __builtin_amdgcn_mfma_f32_16x16x32_bf16(fah[mi], fbh[ni], acc[mi][ni], 0, 0, 0);
          acc[mi][ni] = __builtin_amdgcn_mfma_f32_16x16x32_bf16(fah[mi], fbl[ni], acc[mi][ni], 0, 0, 0);
          acc[mi][ni] = __builtin_amdgcn_mfma_f32_16x16x32_bf16(fal[mi], fbh[ni], acc[mi][ni], 0, 0, 0);
        }
      __builtin_amdgcn_s_setprio(0);
      __builtin_amdgcn_sched_barrier(0);
      __builtin_amdgcn_s_barrier();
    }
  } else {
    // fp32 A tile in buf[0,16K): 128B rows, 8-slot XOR swizzle
    size_t aS[4]; int aL[4];
#pragma unroll
    for (int is = 0; is < 4; ++is) {
      int off = is * 4096 + tid * 16;
      int r = off >> 7;
      int sl = (off >> 4) & 7;
      int col = ((sl ^ (r & 7)) << 2);      // floats
      aS[is] = (arow0 + r) * KDIM + col;
      aL[is] = is * 4096 + w * 1024;
    }
    int a1[4], a2[4];
#pragma unroll
    for (int mi = 0; mi < 4; ++mi) {
      int row = wr * 64 + mi * 16 + fr;
      a1[mi] = row * 128 + (((fq << 1)     ^ (row & 7)) << 4);
      a2[mi] = row * 128 + (((fq << 1) + 1) ^ (row & 7)) * 16;
    }

    auto STAGE = [&](int buf, int k0) {     // 8 gld16 / thread
      char* b = smem + buf * 32768;
#pragma unroll
      for (int is = 0; is < 4; ++is) gld16(Af + aS[is] + k0, b + aL[is]);
#pragma unroll
      for (int is = 0; is < 2; ++is) {
        gld16(Bh + bS[is] + k0, b + 16384 + bL[is]);
        gld16(Bl + bS[is] + k0, b + 24576 + bL[is]);
      }
    };

    STAGE(0, 0);
    for (int t = 0; t < NK; ++t) {
      char* bufc = smem + (t & 1) * 32768;
      if (t + 1 < NK) {
        STAGE((t + 1) & 1, (t + 1) * BK);
        asm volatile("s_waitcnt vmcnt(8)" ::: "memory");
      } else {
        asm volatile("s_waitcnt vmcnt(0)" ::: "memory");
      }
      __builtin_amdgcn_s_barrier();
      __builtin_amdgcn_sched_barrier(0);

      bf16x8 fah[4], fal[4], fbh[4], fbl[4];
#pragma unroll
      for (int ni = 0; ni < 4; ++ni) {
        fbh[ni] = *(const bf16x8*)(bufc + 16384 + bOff[ni]);
        fbl[ni] = *(const bf16x8*)(bufc + 24576 + bOff[ni]);
      }
#pragma unroll
      for (int mi = 0; mi < 4; ++mi) {
        float4 v1 = *(const float4*)(bufc + a1[mi]);
        float4 v2 = *(const float4*)(bufc + a2[mi]);
        float f[8] = {v1.x, v1.y, v1.z, v1.w, v2.x, v2.y, v2.z, v2.w};
        union { bf16x8 v; unsigned short u[8]; } H, L;
#pragma unroll
        for (int q = 0; q < 8; ++q) {
          unsigned short hq = f2bf(f[q]);
          H.u[q] = hq;
          L.u[q] = f2bf(f[q] - bf2f(hq));
        }
        fah[mi] = H.v;
        fal[mi] = L.v;
      }
      __builtin_amdgcn_s_setprio(1);
#pragma unroll
      for (int mi = 0; mi < 4; ++mi)
#pragma unroll
        for (int ni = 0; ni < 4; ++ni) {
          acc[mi][ni] = __builtin_amdgcn_mfma_f32_16x16x32_bf16(fah[mi], fbh[ni], acc[mi][ni], 0, 0, 0);
          acc[mi][ni] = __builtin_amdgcn_mfma_f32_16x16x32_bf16(fah[mi], fbl[ni], acc[mi][ni], 0, 0, 0);
          acc[mi][ni] = __builtin_amdgcn_mfma_f32_16x16x32_bf16(fal[mi], fbh[ni], acc[mi][ni], 0, 0, 0);
        }
      __builtin_amdgcn_s_setprio(0);
      __builtin_amdgcn_sched_barrier(0);
      __builtin_amdgcn_s_barrier();
    }
  }

  // ---- epilogue: acc -> LDS -> linear coalesced P stores
  // frag layout: row = wr*64 + mi*16 + fq*4 + j, col = wc*64 + ni*16 + fr
  float* ep = (float*)smem;
  __syncthreads();
#pragma unroll
  for (int half = 0; half < 2; ++half) {
    if (wr == half) {
#pragma unroll
      for (int mi = 0; mi < 4; ++mi)
#pragma unroll
        for (int ni = 0; ni < 4; ++ni)
#pragma unroll
          for (int j = 0; j < 4; ++j) {
            int r = mi * 16 + fq * 4 + j;
            int c = wc * 64 + ni * 16 + fr;
            ep[r * EPS + c] = acc[mi][ni][j];
          }
    }
    __syncthreads();
    for (int i = tid; i < 2048; i += 256) {
      int r = i >> 5;
      int c4 = (i & 31) << 2;
      float4 v = *(const float4*)&ep[r * EPS + c4];
      *(float4*)&P[(arow0 + half * 64 + r) * NDIM + brow0 + c4] = v;
    }
    __syncthreads();
  }
}

// ---------------- pass 2: streaming gather/write ----------------
// out[t] = relu(P[word_ids[t]] + Hc[char_ids[t]]), t in order -> sequential writes.
__global__ __launch_bounds__(256) void k_out(const int* __restrict__ wid,
                                             const int* __restrict__ cid,
                                             const float* __restrict__ P,
                                             const float* __restrict__ Hc,
                                             float* __restrict__ out) {
  int w = threadIdx.x >> 6, lane = threadIdx.x & 63;
  int t0 = blockIdx.x * 64 + w * 16;
  int wd = wid[t0], cd = cid[t0];
#pragma unroll 4
  for (int i = 0; i < 16; ++i) {
    int t = t0 + i;
    int wdn = wd, cdn = cd;
    if (i < 15) { wdn = wid[t + 1]; cdn = cid[t + 1]; }
    const float4* pr = (const float4*)&P[(size_t)wd << 10];
    const float4* hr = (const float4*)&Hc[(size_t)cd << 10];
    float* orow = &out[(size_t)t << 10];
#pragma unroll
    for (int ch = 0; ch < 4; ++ch) {
      int c = ch * 64 + lane;               // float4 index within row
      float4 a = pr[c];
      float4 b = hr[c];
      nt_store_f2(&orow[c * 4],     fmaxf(a.x + b.x, 0.f), fmaxf(a.y + b.y, 0.f));
      nt_store_f2(&orow[c * 4 + 2], fmaxf(a.z + b.z, 0.f), fmaxf(a.w + b.w, 0.f));
    }
    wd = wdn; cd = cdn;
  }
}

// ---------------- Plan C fallback: R5 scatter kernel (preconv) ----------------
__global__ __launch_bounds__(256, 2) void k_gemm_scatter(
    const unsigned short* __restrict__ Ah, const unsigned short* __restrict__ Al,
    const unsigned short* __restrict__ Bh, const unsigned short* __restrict__ Bl,
    const float* __restrict__ Hc, const int* __restrict__ offs,
    const unsigned int* __restrict__ perm,
    float* __restrict__ out) {
  __shared__ __align__(16) char smem[65536];

  int nwg = gridDim.x;
  int bid = blockIdx.x;
  int cpx = nwg >> 3;
  int swz = (bid & 7) * cpx + (bid >> 3);
  int bn = swz & 7;
  int bm = swz >> 3;

  int tid = threadIdx.x;
  int lane = tid & 63;
  int w = tid >> 6;
  int wr = w >> 1, wc = w & 1;
  int fr = lane & 15, fq = lane >> 4;

  size_t arow0 = (size_t)bm * BM;
  size_t brow0 = (size_t)bn * BN;

  f32x4 acc[4][4];
#pragma unroll
  for (int i = 0; i < 4; ++i)
#pragma unroll
    for (int j = 0; j < 4; ++j) acc[i][j] = (f32x4)0.0f;

  size_t aSrc[2], bSrc[2];
  int ldsOff[2];
#pragma unroll
  for (int is = 0; is < 2; ++is) {
    int off = is * 4096 + tid * 16;
    int r = off >> 6;
    int sp = (off >> 4) & 3;
    int colE = ((sp ^ ((r >> 1) & 3)) << 3);
    aSrc[is] = (arow0 + r) * KDIM + colE;
    bSrc[is] = (brow0 + r) * KDIM + colE;
    ldsOff[is] = is * 4096 + w * 1024;
  }
  int aOff[4], bOff[4];
#pragma unroll
  for (int mi = 0; mi < 4; ++mi) {
    int row = wr * 64 + mi * 16 + fr;
    aOff[mi] = row * 64 + ((fq ^ ((row >> 1) & 3)) << 4);
  }
#pragma unroll
  for (int ni = 0; ni < 4; ++ni) {
    int row = wc * 64 + ni * 16 + fr;
    bOff[ni] = row * 64 + ((fq ^ ((row >> 1) & 3)) << 4);
  }

  auto STAGE = [&](int buf, int k0) {
    char* b = smem + buf * 32768;
#pragma unroll
    for (int is = 0; is < 2; ++is) {
      gld16(Ah + aSrc[is] + k0, b + ldsOff[is]);
      gld16(Al + aSrc[is] + k0, b + 8192 + ldsOff[is]);
      gld16(Bh + bSrc[is] + k0, b + 16384 + ldsOff[is]);
      gld16(Bl + bSrc[is] + k0, b + 24576 + ldsOff[is]);
    }
  };

  STAGE(0, 0);
  for (int t = 0; t < NK; ++t) {
    char* bufc = smem + (t & 1) * 32768;
    if (t + 1 < NK) {
      STAGE((t + 1) & 1, (t + 1) * BK);
      asm volatile("s_waitcnt vmcnt(8)" ::: "memory");
    } else {
      asm volatile("s_waitcnt vmcnt(0)" ::: "memory");
    }
    __builtin_amdgcn_s_barrier();
    __builtin_amdgcn_sched_barrier(0);

    bf16x8 fah[4], fal[4], fbh[4], fbl[4];
#pragma unroll
    for (int ni = 0; ni < 4; ++ni) {
      fbh[ni] = *(const bf16x8*)(bufc + 16384 + bOff[ni]);
      fbl[ni] = *(const bf16x8*)(bufc + 24576 + bOff[ni]);
    }
#pragma unroll
    for (int mi = 0; mi < 4; ++mi) {
      fah[mi] = *(const bf16x8*)(bufc + aOff[mi]);
      fal[mi] = *(const bf16x8*)(bufc + 8192 + aOff[mi]);
    }
    __builtin_amdgcn_s_setprio(1);
#pragma unroll
    for (int mi = 0; mi < 4; ++mi)
#pragma unroll
      for (int ni = 0; ni < 4; ++ni) {
        acc[mi][ni] = __builtin_amdgcn_mfma_f32_16x16x32_bf16(fah[mi], fbh[ni], acc[mi][ni], 0, 0, 0);
        acc[mi][ni] = __builtin_amdgcn_mfma_f32_16x16x32_bf16(fah[mi], fbl[ni], acc[mi][ni], 0, 0, 0);
        acc[mi][ni] = __builtin_amdgcn_mfma_f32_16x16x32_bf16(fal[mi], fbh[ni], acc[mi][ni], 0, 0, 0);
      }
    __builtin_amdgcn_s_setprio(0);
    __builtin_amdgcn_sched_barrier(0);
    __builtin_amdgcn_s_barrier();
  }

  float* ep = (float*)smem;
  float* hs = (float*)(smem + HCOFF);
  __syncthreads();
  for (int i = tid; i < NEMB * 32; i += 256) {
    int rr = i >> 5;
    int cc = (i & 31) << 2;
    *(float4*)&hs[rr * 128 + cc] = *(const float4*)&Hc[(size_t)rr * NDIM + brow0 + cc];
  }
#pragma unroll
  for (int half = 0; half < 2; ++half) {
    if (wr == half) {
#pragma unroll
      for (int mi = 0; mi < 4; ++mi)
#pragma unroll
        for (int ni = 0; ni < 4; ++ni)
#pragma unroll
          for (int j = 0; j < 4; ++j) {
            int r = mi * 16 + fq * 4 + j;
            int c = wc * 64 + ni * 16 + fr;
            ep[r * EPS + c] = acc[mi][ni][j];
          }
    }
    __syncthreads();
    for (int m = w; m < 64; m += 4) {
      int gm = (int)arow0 + half * 64 + m;
      int beg = offs[gm];
      int end = offs[gm + 1];
      if (beg == end) continue;
      float2 pv = *(const float2*)&ep[m * EPS + lane * 2];
      unsigned int v = perm[beg];
      for (int p = beg; p < end; ++p) {
        int pn = (p + 1 < end) ? p + 1 : p;
        unsigned int vn = perm[pn];
        int t = (int)(v >> 6);
        int c = (int)(v & 63u);
        float2 hv = *(const float2*)&hs[c * 128 + lane * 2];
        nt_store_f2(&out[(size_t)t * NDIM + brow0 + lane * 2],
                    fmaxf(pv.x + hv.x, 0.f), fmaxf(pv.y + hv.y, 0.f));
        v = vn;
      }
    }
    __syncthreads();
  }
}

extern "C" void kernel_launch(void* const* d_in, const int* in_sizes, int n_in,
                              void* d_out, int out_size, void* d_ws, size_t ws_size,
                              hipStream_t stream) {
  (void)in_sizes; (void)n_in; (void)out_size;
  const float* word_emb = (const float*)d_in[0];
  const int*   char_ids = (const int*)d_in[1];
  const int*   word_ids = (const int*)d_in[2];
  const float* E        = (const float*)d_in[3];
  const float* W_ih     = (const float*)d_in[4];
  const float* b_ih     = (const float*)d_in[5];
  const float* b_hh     = (const float*)d_in[6];
  const float* W_lin    = (const float*)d_in[7];
  const float* b_lin    = (const float*)d_in[8];
  float* out = (float*)d_out;
  char* ws = (char*)d_ws;

  size_t o = 0;
  auto alloc = [&](size_t b) { size_t r = o; o = (o + b + 255) & ~(size_t)255; return r; };
  size_t oHc = alloc((size_t)NEMB * NDIM * 4);
  size_t oH  = alloc((size_t)NEMB * HID * 4);
  size_t oBh = alloc((size_t)NDIM * KDIM * 2);
  size_t oBl = alloc((size_t)NDIM * KDIM * 2);
  size_t baseEnd = o;
  size_t oP  = alloc((size_t)NWORDS * NDIM * 4);
  size_t szB = o;
  size_t oAh = alloc((size_t)NWORDS * KDIM * 2);
  size_t oAl = alloc((size_t)NWORDS * KDIM * 2);
  size_t szA = o;
  // Plan C layout overlays the P/Ah/Al region
  size_t c = baseEnd;
  auto allocC = [&](size_t b) { size_t r = c; c = (c + b + 255) & ~(size_t)255; return r; };
  size_t oCnt  = allocC((size_t)NWORDS * 4);
  size_t oOffs = allocC((size_t)(NWORDS + 1) * 4);
  size_t oCur  = allocC((size_t)NWORDS * 4);
  size_t oPerm = allocC((size_t)T_TOTAL * 4);
  size_t oAhC  = allocC((size_t)NWORDS * KDIM * 2);
  size_t oAlC  = allocC((size_t)NWORDS * KDIM * 2);

  float* Hc          = (float*)(ws + oHc);
  float* hbuf        = (float*)(ws + oH);
  unsigned short* Bh = (unsigned short*)(ws + oBh);
  unsigned short* Bl = (unsigned short*)(ws + oBl);

  // shared prep: LSTM table + B split
  k_prep_h<<<NEMB, 256, 0, stream>>>(E, W_ih, b_ih, b_hh, hbuf);
  k_prep_hc2<<<NEMB * 4, 256, 0, stream>>>(hbuf, W_lin, b_lin, Hc);
  k_conv<<<(NDIM * KDIM / 4) / 256, 256, 0, stream>>>(W_lin, 1536L, Bh, Bl);

  int grid = (NWORDS / BM) * (NDIM / BN);  // 2048

  if (ws_size >= szB) {
    float* P = (float*)(ws + oP);
    if (ws_size >= szA) {
      unsigned short* Ah = (unsigned short*)(ws + oAh);
      unsigned short* Al = (unsigned short*)(ws + oAl);
      k_conv<<<((size_t)NWORDS * KDIM / 4) / 256, 256, 0, stream>>>(word_emb, 1024L, Ah, Al);
      k_gemm_p<true><<<grid, 256, 0, stream>>>(word_emb, Ah, Al, Bh, Bl, P);
    } else {
      k_gemm_p<false><<<grid, 256, 0, stream>>>(word_emb, nullptr, nullptr, Bh, Bl, P);
    }
    k_out<<<T_TOTAL / 64, 256, 0, stream>>>(word_ids, char_ids, P, Hc, out);
  } else {
    int* cnt   = (int*)(ws + oCnt);
    int* offsp = (int*)(ws + oOffs);
    int* cur   = (int*)(ws + oCur);
    unsigned int* perm = (unsigned int*)(ws + oPerm);
    unsigned short* Ah = (unsigned short*)(ws + oAhC);
    unsigned short* Al = (unsigned short*)(ws + oAlC);
    k_zero<<<(NWORDS + 255) / 256, 256, 0, stream>>>(cnt, NWORDS);
    k_hist<<<T_TOTAL / 256, 256, 0, stream>>>(word_ids, cnt);
    k_scan<<<1, 1024, 0, stream>>>(cnt, offsp, cur);
    k_scatter<<<T_TOTAL / 256, 256, 0, stream>>>(word_ids, char_ids, cur, perm);
    k_conv<<<((size_t)NWORDS * KDIM / 4) / 256, 256, 0, stream>>>(word_emb, 1024L, Ah, Al);
    k_gemm_scatter<<<grid, 256, 0, stream>>>(Ah, Al, Bh, Bl, Hc, offsp, perm, out);
  }
}

// Round 7
// 482.782 us; speedup vs baseline: 1.4685x; 1.0690x over previous
//
#include <hip/hip_runtime.h>
#include <cstdint>
#include <cstddef>

#define T_TOTAL   131072
#define NWORDS    32768
#define WDIM      1024
#define CDIM      256
#define HID       512
#define NEMB      40
#define KDIM      1024
#define NDIM      1024

#define BM 128
#define BN 128
#define BK 32
#define NK (KDIM / BK)
#define EPS 132   // epilogue LDS row stride (floats): 528B -> bank-even

#define NCONVB_BLKS (NDIM * KDIM / 4 / 256)          // 1024
#define NCONVA_BLKS (NWORDS * KDIM / 4 / 256)        // 32768

typedef __attribute__((ext_vector_type(8))) short bf16x8;
typedef __attribute__((ext_vector_type(4))) float f32x4;
typedef __attribute__((ext_vector_type(4))) unsigned short u16x4;

__device__ __forceinline__ unsigned short f2bf(float x) {
  union { float f; unsigned int u; } v; v.f = x;
  unsigned int r = v.u + 0x7fffu + ((v.u >> 16) & 1u);   // RNE
  return (unsigned short)(r >> 16);
}
__device__ __forceinline__ float bf2f(unsigned short b) {
  union { float f; unsigned int u; } v; v.u = ((unsigned int)b) << 16;
  return v.f;
}

__device__ __forceinline__ void gld16(const void* src, void* lds) {
  __builtin_amdgcn_global_load_lds(
      (const __attribute__((address_space(1))) unsigned int*)src,
      (__attribute__((address_space(3))) unsigned int*)lds, 16, 0, 0);
}

// ---------------- fused prep: LSTM->Hc, W_lin->Bh/Bl, word_emb->Ah/Al ----------------
template <bool DO_A>
__global__ __launch_bounds__(256) void k_prep(
    const float* __restrict__ word_emb, const float* __restrict__ E,
    const float* __restrict__ W_ih, const float* __restrict__ b_ih,
    const float* __restrict__ b_hh, const float* __restrict__ W_lin,
    const float* __restrict__ b_lin,
    unsigned short* __restrict__ Ah, unsigned short* __restrict__ Al,
    unsigned short* __restrict__ Bh, unsigned short* __restrict__ Bl,
    float* __restrict__ Hc) {
  __shared__ float sx[CDIM];
  __shared__ float sh[HID];
  int b = blockIdx.x;
  int tid = threadIdx.x;

  if (b < NEMB) {
    // ---- fused LSTM cell (zero state) + Hc row: Hc[e] = W2 @ h + b_lin
    int e = b;
    sx[tid] = E[e * CDIM + tid];
    __syncthreads();
    const float4* xv = (const float4*)sx;
#pragma unroll
    for (int rep = 0; rep < 2; ++rep) {
      int j = rep * 256 + tid;                       // j in [0,512)
      float si = b_ih[j] + b_hh[j];
      float sg = b_ih[1024 + j] + b_hh[1024 + j];
      float so = b_ih[1536 + j] + b_hh[1536 + j];
      const float4* wi = (const float4*)&W_ih[(size_t)j * CDIM];
      const float4* wg = (const float4*)&W_ih[(size_t)(1024 + j) * CDIM];
      const float4* wo = (const float4*)&W_ih[(size_t)(1536 + j) * CDIM];
      for (int k = 0; k < CDIM / 4; ++k) {
        float4 d = xv[k];
        float4 a = wi[k]; si += a.x*d.x + a.y*d.y + a.z*d.z + a.w*d.w;
        float4 g = wg[k]; sg += g.x*d.x + g.y*d.y + g.z*d.z + g.w*d.w;
        float4 c = wo[k]; so += c.x*d.x + c.y*d.y + c.z*d.z + c.w*d.w;
      }
      float iv = 1.f / (1.f + expf(-si));
      float cv = iv * tanhf(sg);
      float ov = 1.f / (1.f + expf(-so));
      sh[j] = ov * tanhf(cv);
    }
    __syncthreads();
    const float4* hv = (const float4*)sh;
#pragma unroll
    for (int rep = 0; rep < 4; ++rep) {
      int n = rep * 256 + tid;
      float s = b_lin[n];
      const float4* wl = (const float4*)&W_lin[(size_t)n * 1536 + 1024];
      for (int k = 0; k < HID / 4; ++k) {
        float4 a = wl[k], d = hv[k];
        s += a.x*d.x + a.y*d.y + a.z*d.z + a.w*d.w;
      }
      Hc[e * NDIM + n] = s;
    }
    return;
  }
  b -= NEMB;
  if (b < NCONVB_BLKS) {
    // ---- W_lin cols [0,1024) -> Bh/Bl (hi/lo bf16 split)
    long idx = ((long)b * 256 + tid) * 4;
    long r = idx >> 10;
    int c = (int)(idx & 1023);
    const float4 v = *(const float4*)&W_lin[r * 1536 + c];
    unsigned short h0 = f2bf(v.x), h1 = f2bf(v.y), h2 = f2bf(v.z), h3 = f2bf(v.w);
    u16x4 H = {h0, h1, h2, h3};
    u16x4 L = {f2bf(v.x - bf2f(h0)), f2bf(v.y - bf2f(h1)),
               f2bf(v.z - bf2f(h2)), f2bf(v.w - bf2f(h3))};
    *(u16x4*)&Bh[idx] = H;
    *(u16x4*)&Bl[idx] = L;
    return;
  }
  if (DO_A) {
    // ---- word_emb (contiguous 32768x1024) -> Ah/Al
    b -= NCONVB_BLKS;
    long idx = ((long)b * 256 + tid) * 4;
    const float4 v = *(const float4*)&word_emb[idx];
    unsigned short h0 = f2bf(v.x), h1 = f2bf(v.y), h2 = f2bf(v.z), h3 = f2bf(v.w);
    u16x4 H = {h0, h1, h2, h3};
    u16x4 L = {f2bf(v.x - bf2f(h0)), f2bf(v.y - bf2f(h1)),
               f2bf(v.z - bf2f(h2)), f2bf(v.w - bf2f(h3))};
    *(u16x4*)&Ah[idx] = H;
    *(u16x4*)&Al[idx] = L;
  }
}

// ---------------- GEMM (dedup'd words) -> P[32768][1024] ----------------
// P[m][n] = sum_k we[m][k] * W_lin[n][k] via split-bf16 3-MFMA emulation.
// 256 thr / 4 waves (2x2, wave tile 64x64), 2 x 32KB dbuf, counted vmcnt.
// XOR slot-swizzle on the GLOBAL source (LDS dest linear, required by
// global_load_lds) and on the fragment reads -> 0 bank conflicts.
template <bool PRECONV>
__global__ __launch_bounds__(256, 2) void k_gemm_p(
    const float* __restrict__ Af,
    const unsigned short* __restrict__ Ah, const unsigned short* __restrict__ Al,
    const unsigned short* __restrict__ Bh, const unsigned short* __restrict__ Bl,
    float* __restrict__ P) {
  __shared__ __align__(16) char smem[65536];

  int nwg = gridDim.x;
  int bid = blockIdx.x;
  int cpx = nwg >> 3;
  int swz = (bid & 7) * cpx + (bid >> 3);
  int bn = swz & 7;
  int bm = swz >> 3;

  int tid = threadIdx.x;
  int lane = tid & 63;
  int w = tid >> 6;
  int wr = w >> 1, wc = w & 1;
  int fr = lane & 15, fq = lane >> 4;

  size_t arow0 = (size_t)bm * BM;
  size_t brow0 = (size_t)bn * BN;

  f32x4 acc[4][4];
#pragma unroll
  for (int i = 0; i < 4; ++i)
#pragma unroll
    for (int j = 0; j < 4; ++j) acc[i][j] = (f32x4)0.0f;

  int bOff[4];
#pragma unroll
  for (int ni = 0; ni < 4; ++ni) {
    int row = wc * 64 + ni * 16 + fr;
    bOff[ni] = row * 64 + ((fq ^ ((row >> 1) & 3)) << 4);
  }
  size_t bS[2]; int bL[2];
#pragma unroll
  for (int is = 0; is < 2; ++is) {
    int off = is * 4096 + tid * 16;
    int r = off >> 6;
    int sp = (off >> 4) & 3;
    int colE = ((sp ^ ((r >> 1) & 3)) << 3);
    bS[is] = (brow0 + r) * KDIM + colE;
    bL[is] = is * 4096 + w * 1024;
  }

  if (PRECONV) {
    size_t aS[2];
#pragma unroll
    for (int is = 0; is < 2; ++is) {
      int off = is * 4096 + tid * 16;
      int r = off >> 6;
      int sp = (off >> 4) & 3;
      int colE = ((sp ^ ((r >> 1) & 3)) << 3);
      aS[is] = (arow0 + r) * KDIM + colE;
    }
    int aOff[4];
#pragma unroll
    for (int mi = 0; mi < 4; ++mi) {
      int row = wr * 64 + mi * 16 + fr;
      aOff[mi] = row * 64 + ((fq ^ ((row >> 1) & 3)) << 4);
    }

    auto STAGE = [&](int buf, int k0) {     // 8 gld16 / thread
      char* b = smem + buf * 32768;
#pragma unroll
      for (int is = 0; is < 2; ++is) {
        gld16(Ah + aS[is] + k0, b + bL[is]);
        gld16(Al + aS[is] + k0, b + 8192 + bL[is]);
        gld16(Bh + bS[is] + k0, b + 16384 + bL[is]);
        gld16(Bl + bS[is] + k0, b + 24576 + bL[is]);
      }
    };

    STAGE(0, 0);
    for (int t = 0; t < NK; ++t) {
      char* bufc = smem + (t & 1) * 32768;
      if (t + 1 < NK) {
        STAGE((t + 1) & 1, (t + 1) * BK);
        asm volatile("s_waitcnt vmcnt(8)" ::: "memory");
      } else {
        asm volatile("s_waitcnt vmcnt(0)" ::: "memory");
      }
      __builtin_amdgcn_s_barrier();
      __builtin_amdgcn_sched_barrier(0);

      bf16x8 fah[4], fal[4], fbh[4], fbl[4];
#pragma unroll
      for (int ni = 0; ni < 4; ++ni) {
        fbh[ni] = *(const bf16x8*)(bufc + 16384 + bOff[ni]);
        fbl[ni] = *(const bf16x8*)(bufc + 24576 + bOff[ni]);
      }
#pragma unroll
      for (int mi = 0; mi < 4; ++mi) {
        fah[mi] = *(const bf16x8*)(bufc + aOff[mi]);
        fal[mi] = *(const bf16x8*)(bufc + 8192 + aOff[mi]);
      }
      __builtin_amdgcn_s_setprio(1);
#pragma unroll
      for (int mi = 0; mi < 4; ++mi)
#pragma unroll
        for (int ni = 0; ni < 4; ++ni) {
          acc[mi][ni] = __builtin_amdgcn_mfma_f32_16x16x32_bf16(fah[mi], fbh[ni], acc[mi][ni], 0, 0, 0);
          acc[mi][ni] = __builtin_amdgcn_mfma_f32_16x16x32_bf16(fah[mi], fbl[ni], acc[mi][ni], 0, 0, 0);
          acc[mi][ni] = __builtin_amdgcn_mfma_f32_16x16x32_bf16(fal[mi], fbh[ni], acc[mi][ni], 0, 0, 0);
        }
      __builtin_amdgcn_s_setprio(0);
      __builtin_amdgcn_sched_barrier(0);
      __builtin_amdgcn_s_barrier();
    }
  } else {
    // fp32 A tile in buf[0,16K): 128B rows, 8-slot XOR swizzle, split in-kernel
    size_t aS[4]; int aL[4];
#pragma unroll
    for (int is = 0; is < 4; ++is) {
      int off = is * 4096 + tid * 16;
      int r = off >> 7;
      int sl = (off >> 4) & 7;
      int col = ((sl ^ (r & 7)) << 2);      // floats
      aS[is] = (arow0 + r) * KDIM + col;
      aL[is] = is * 4096 + w * 1024;
    }
    int a1[4], a2[4];
#pragma unroll
    for (int mi = 0; mi < 4; ++mi) {
      int row = wr * 64 + mi * 16 + fr;
      a1[mi] = row * 128 + (((fq << 1)     ^ (row & 7)) << 4);
      a2[mi] = row * 128 + (((fq << 1) + 1) ^ (row & 7)) * 16;
    }

    auto STAGE = [&](int buf, int k0) {
      char* b = smem + buf * 32768;
#pragma unroll
      for (int is = 0; is < 4; ++is) gld16(Af + aS[is] + k0, b + aL[is]);
#pragma unroll
      for (int is = 0; is < 2; ++is) {
        gld16(Bh + bS[is] + k0, b + 16384 + bL[is]);
        gld16(Bl + bS[is] + k0, b + 24576 + bL[is]);
      }
    };

    STAGE(0, 0);
    for (int t = 0; t < NK; ++t) {
      char* bufc = smem + (t & 1) * 32768;
      if (t + 1 < NK) {
        STAGE((t + 1) & 1, (t + 1) * BK);
        asm volatile("s_waitcnt vmcnt(8)" ::: "memory");
      } else {
        asm volatile("s_waitcnt vmcnt(0)" ::: "memory");
      }
      __builtin_amdgcn_s_barrier();
      __builtin_amdgcn_sched_barrier(0);

      bf16x8 fah[4], fal[4], fbh[4], fbl[4];
#pragma unroll
      for (int ni = 0; ni < 4; ++ni) {
        fbh[ni] = *(const bf16x8*)(bufc + 16384 + bOff[ni]);
        fbl[ni] = *(const bf16x8*)(bufc + 24576 + bOff[ni]);
      }
#pragma unroll
      for (int mi = 0; mi < 4; ++mi) {
        float4 v1 = *(const float4*)(bufc + a1[mi]);
        float4 v2 = *(const float4*)(bufc + a2[mi]);
        float f[8] = {v1.x, v1.y, v1.z, v1.w, v2.x, v2.y, v2.z, v2.w};
        union { bf16x8 v; unsigned short u[8]; } H, L;
#pragma unroll
        for (int q = 0; q < 8; ++q) {
          unsigned short hq = f2bf(f[q]);
          H.u[q] = hq;
          L.u[q] = f2bf(f[q] - bf2f(hq));
        }
        fah[mi] = H.v;
        fal[mi] = L.v;
      }
      __builtin_amdgcn_s_setprio(1);
#pragma unroll
      for (int mi = 0; mi < 4; ++mi)
#pragma unroll
        for (int ni = 0; ni < 4; ++ni) {
          acc[mi][ni] = __builtin_amdgcn_mfma_f32_16x16x32_bf16(fah[mi], fbh[ni], acc[mi][ni], 0, 0, 0);
          acc[mi][ni] = __builtin_amdgcn_mfma_f32_16x16x32_bf16(fah[mi], fbl[ni], acc[mi][ni], 0, 0, 0);
          acc[mi][ni] = __builtin_amdgcn_mfma_f32_16x16x32_bf16(fal[mi], fbh[ni], acc[mi][ni], 0, 0, 0);
        }
      __builtin_amdgcn_s_setprio(0);
      __builtin_amdgcn_sched_barrier(0);
      __builtin_amdgcn_s_barrier();
    }
  }

  // ---- epilogue: acc -> LDS -> linear coalesced P stores
  float* ep = (float*)smem;
  __syncthreads();
#pragma unroll
  for (int half = 0; half < 2; ++half) {
    if (wr == half) {
#pragma unroll
      for (int mi = 0; mi < 4; ++mi)
#pragma unroll
        for (int ni = 0; ni < 4; ++ni)
#pragma unroll
          for (int j = 0; j < 4; ++j) {
            int r = mi * 16 + fq * 4 + j;
            int c = wc * 64 + ni * 16 + fr;
            ep[r * EPS + c] = acc[mi][ni][j];
          }
    }
    __syncthreads();
    for (int i = tid; i < 2048; i += 256) {
      int r = i >> 5;
      int c4 = (i & 31) << 2;
      float4 v = *(const float4*)&ep[r * EPS + c4];
      *(float4*)&P[(arow0 + half * 64 + r) * NDIM + brow0 + c4] = v;
    }
    __syncthreads();
  }
}

// ---------------- pass 2: streaming gather/write (warp-per-row) ----------------
// out[t] = relu(P[word_ids[t]] + Hc[char_ids[t]]), t in order -> sequential writes.
__global__ __launch_bounds__(256) void k_out(const int* __restrict__ wid,
                                             const int* __restrict__ cid,
                                             const float* __restrict__ P,
                                             const float* __restrict__ Hc,
                                             float* __restrict__ out) {
  int w = threadIdx.x >> 6, lane = threadIdx.x & 63;
  int t = blockIdx.x * 4 + w;
  int wd = wid[t], cd = cid[t];
  const f32x4* pr = (const f32x4*)&P[(size_t)wd << 10];
  const f32x4* hr = (const f32x4*)&Hc[(size_t)cd << 10];
  f32x4* orow = (f32x4*)&out[(size_t)t << 10];
#pragma unroll
  for (int ch = 0; ch < 4; ++ch) {
    int c = ch * 64 + lane;
    f32x4 a = pr[c];
    f32x4 h4 = hr[c];
    f32x4 r;
    r[0] = fmaxf(a[0] + h4[0], 0.f);
    r[1] = fmaxf(a[1] + h4[1], 0.f);
    r[2] = fmaxf(a[2] + h4[2], 0.f);
    r[3] = fmaxf(a[3] + h4[3], 0.f);
    __builtin_nontemporal_store(r, &orow[c]);
  }
}

extern "C" void kernel_launch(void* const* d_in, const int* in_sizes, int n_in,
                              void* d_out, int out_size, void* d_ws, size_t ws_size,
                              hipStream_t stream) {
  (void)in_sizes; (void)n_in; (void)out_size;
  const float* word_emb = (const float*)d_in[0];
  const int*   char_ids = (const int*)d_in[1];
  const int*   word_ids = (const int*)d_in[2];
  const float* E        = (const float*)d_in[3];
  const float* W_ih     = (const float*)d_in[4];
  const float* b_ih     = (const float*)d_in[5];
  const float* b_hh     = (const float*)d_in[6];
  const float* W_lin    = (const float*)d_in[7];
  const float* b_lin    = (const float*)d_in[8];
  float* out = (float*)d_out;
  char* ws = (char*)d_ws;

  size_t o = 0;
  auto alloc = [&](size_t b) { size_t r = o; o = (o + b + 255) & ~(size_t)255; return r; };
  size_t oHc = alloc((size_t)NEMB * NDIM * 4);
  size_t oBh = alloc((size_t)NDIM * KDIM * 2);
  size_t oBl = alloc((size_t)NDIM * KDIM * 2);
  size_t oP  = alloc((size_t)NWORDS * NDIM * 4);
  size_t szB = o;
  size_t oAh = alloc((size_t)NWORDS * KDIM * 2);
  size_t oAl = alloc((size_t)NWORDS * KDIM * 2);
  size_t szA = o;

  float* Hc          = (float*)(ws + oHc);
  unsigned short* Bh = (unsigned short*)(ws + oBh);
  unsigned short* Bl = (unsigned short*)(ws + oBl);
  float* P           = (float*)(ws + oP);
  unsigned short* Ah = (unsigned short*)(ws + oAh);
  unsigned short* Al = (unsigned short*)(ws + oAl);

  int grid = (NWORDS / BM) * (NDIM / BN);  // 2048

  if (ws_size >= szA) {
    k_prep<true><<<NEMB + NCONVB_BLKS + NCONVA_BLKS, 256, 0, stream>>>(
        word_emb, E, W_ih, b_ih, b_hh, W_lin, b_lin, Ah, Al, Bh, Bl, Hc);
    k_gemm_p<true><<<grid, 256, 0, stream>>>(word_emb, Ah, Al, Bh, Bl, P);
  } else {
    // Plan B: no pre-split A; stage fp32 A and split in-kernel (ws >= szB,
    // guaranteed: harness ws is ~2 GiB per poison-fill evidence).
    k_prep<false><<<NEMB + NCONVB_BLKS, 256, 0, stream>>>(
        word_emb, E, W_ih, b_ih, b_hh, W_lin, b_lin, nullptr, nullptr, Bh, Bl, Hc);
    k_gemm_p<false><<<grid, 256, 0, stream>>>(word_emb, nullptr, nullptr, Bh, Bl, P);
  }
  k_out<<<T_TOTAL / 4, 256, 0, stream>>>(word_ids, char_ids, P, Hc, out);
}